// Round 9
// baseline (325.060 us; speedup 1.0000x reference)
//
#include <hip/hip_runtime.h>
#include <hip/hip_bf16.h>

typedef __attribute__((ext_vector_type(8))) short short8;
typedef __attribute__((ext_vector_type(4))) short short4v;
typedef __attribute__((ext_vector_type(4))) float floatx4;
typedef __attribute__((ext_vector_type(2))) unsigned uint2v;
typedef unsigned short u16;

#define NB 32
#define NN 1536
#define NM 80
#define NH 8
#define NC 64
#define NINNER 512
#define NQD 320
#define NKD 768

__device__ __forceinline__ float bf2f(u16 u) {
    union { unsigned i; float f; } x; x.i = ((unsigned)u) << 16; return x.f;
}
__device__ __forceinline__ u16 f2bf(float f) {
    unsigned u = __float_as_uint(f);
    unsigned r = (u + 0x7FFFu + ((u >> 16) & 1u)) >> 16;  // RNE
    return (u16)r;
}
// packed f32x2 -> bf16x2, RNE (identical rounding to f2bf)
__device__ __forceinline__ unsigned cvt_pk_bf16(float lo, float hi) {
    unsigned r;
    asm("v_cvt_pk_bf16_f32 %0, %1, %2" : "=v"(r) : "v"(lo), "v"(hi));
    return r;
}
__device__ __forceinline__ short8 cvt8(const float* __restrict__ p) {
    float4 a = ((const float4*)p)[0];
    float4 b = ((const float4*)p)[1];
    short8 r;
    r[0] = (short)f2bf(a.x); r[1] = (short)f2bf(a.y);
    r[2] = (short)f2bf(a.z); r[3] = (short)f2bf(a.w);
    r[4] = (short)f2bf(b.x); r[5] = (short)f2bf(b.y);
    r[6] = (short)f2bf(b.z); r[7] = (short)f2bf(b.w);
    return r;
}
__device__ __forceinline__ void gload16(const u16* g, u16* l) {
    __builtin_amdgcn_global_load_lds(
        (const __attribute__((address_space(1))) unsigned int*)g,
        (__attribute__((address_space(3))) unsigned int*)l, 16, 0, 0);
}

// ---------------------------------------------------------------------------
// prep: block 0 = input dtype detect (flag=1 means f32 inputs), block 1 =
// mask dtype self-detect + additive bias build.
// ---------------------------------------------------------------------------
__global__ __launch_bounds__(256) void prep(const u16* __restrict__ x,
                                            const unsigned char* __restrict__ raw,
                                            int* __restrict__ flag,
                                            float* __restrict__ maskbias) {
    if (blockIdx.x == 0) {
        __shared__ int cnt;
        if (threadIdx.x == 0) cnt = 0;
        __syncthreads();
        int c = 0;
        for (int i = threadIdx.x; i < 8192; i += 256) {
            unsigned e = (x[i] >> 7) & 0xFF;
            if (e >= 0xA0) c++;
        }
        atomicAdd(&cnt, c);
        __syncthreads();
        if (threadIdx.x == 0) *flag = (cnt > 64) ? 1 : 0;
    } else {
        __shared__ int c_bf, c_f32, c_u8;
        if (threadIdx.x == 0) { c_bf = 0; c_f32 = 0; c_u8 = 0; }
        __syncthreads();
        for (int i = threadIdx.x; i < NB * NM; i += 256) {
            unsigned char v = raw[i];
            if (v == 0x3F && (i & 3) == 1) atomicAdd(&c_bf, 1);
            if (v == 0x3F && (i & 3) == 3) atomicAdd(&c_f32, 1);
            if (v != 0 && (i & 3) != 0) atomicAdd(&c_u8, 1);
        }
        __syncthreads();
        int md;
        if (c_bf > 0) md = 2;
        else if (c_f32 > 0) md = 3;
        else if (c_u8 > 0) md = 1;
        else md = 0;
        for (int i = threadIdx.x; i < NB * NM; i += 256) {
            bool on;
            if (md == 2) on = ((const u16*)raw)[i] != 0;
            else if (md == 3) on = ((const float*)raw)[i] != 0.0f;
            else if (md == 1) on = raw[i] != 0;
            else on = ((const int*)raw)[i] != 0;
            maskbias[i] = on ? 0.0f : -3.4028234663852886e38f;
        }
    }
}

// ---------------------------------------------------------------------------
// Batched f32->bf16 conversion (or u16 copy when flag=0). Seg 6 is the Wo
// pad: elements >= nreal are written as zeros (rows 320..383).
// ---------------------------------------------------------------------------
struct ConvSeg { const void* src; u16* dst; long nreal; long nblk; };
struct ConvArgs { ConvSeg s[7]; };

__global__ __launch_bounds__(256) void conv_batch(ConvArgs a, const int* __restrict__ flag) {
    const int f = *flag;
    long b = blockIdx.x; int seg = 0;
    while (seg < 7 && b >= a.s[seg].nblk) { b -= a.s[seg].nblk; seg++; }
    if (seg >= 7) return;
    const long idx = b * 2048 + threadIdx.x * 8;
    u16* dst = a.s[seg].dst;
    if (idx >= a.s[seg].nreal) { *(short8*)(dst + idx) = (short8)0; return; }
    if (f) *(short8*)(dst + idx) = cvt8((const float*)a.s[seg].src + idx);
    else   *(short8*)(dst + idx) = *(const short8*)((const u16*)a.s[seg].src + idx);
}

// ---------------------------------------------------------------------------
// bf16 MFMA GEMM body, 2-PHASE double-buffered: stage tile t+1 into buf^1
// BEFORE computing tile t from buf, ONE barrier per K-step. 128x128 tile,
// BK=32, 4 waves in 2x2. LDS 2x(A,B) = 32 KiB.  (unchanged)
// ---------------------------------------------------------------------------
template <bool OUT_DYN, bool BIAS>
__device__ __forceinline__ void gemm_body(const u16* __restrict__ A,
                                          const u16* __restrict__ B,
                                          const void* __restrict__ bias,
                                          void* __restrict__ C,
                                          int bx, int by, int Nreal, int K, int f,
                                          u16* As, u16* Bs) {
    const int tid = threadIdx.x;
    const int wave = tid >> 6, lane = tid & 63;
    const int l16 = lane & 15, quad = lane >> 4;
    const int wr = wave >> 1, wc = wave & 1;
    const int bm0 = bx * 128, bn0 = by * 128;

    const int r0 = tid >> 2, c0 = tid & 3;
    const int sc = c0 ^ ((r0 >> 1) & 3);            // swizzled source chunk
    const u16* Ag = A + (size_t)(bm0 + r0) * K + sc * 8;
    const u16* Bg = B + (size_t)(bn0 + r0) * K + sc * 8;

    const int swz = (l16 >> 1) & 3;                 // read-side chunk swizzle
    floatx4 acc[4][4];
#pragma unroll
    for (int i = 0; i < 4; ++i)
#pragma unroll
        for (int n = 0; n < 4; ++n) acc[i][n] = (floatx4)0.0f;

    // prologue: stage K-tile 0 into buffer 0
    {
        u16* AsW = As + wave * 512;
        u16* BsW = Bs + wave * 512;
        gload16(Ag, AsW);                  gload16(Ag + (size_t)64 * K, AsW + 2048);
        gload16(Bg, BsW);                  gload16(Bg + (size_t)64 * K, BsW + 2048);
    }
    __syncthreads();                       // implicit vmcnt(0): tile 0 landed

    int cur = 0;
    for (int kk = 0; kk < K; kk += 32) {
        if (kk + 32 < K) {                 // stage NEXT tile into other buffer
            u16* AsW = As + (cur ^ 1) * 4096 + wave * 512;
            u16* BsW = Bs + (cur ^ 1) * 4096 + wave * 512;
            gload16(Ag + kk + 32, AsW);
            gload16(Ag + (size_t)64 * K + kk + 32, AsW + 2048);
            gload16(Bg + kk + 32, BsW);
            gload16(Bg + (size_t)64 * K + kk + 32, BsW + 2048);
        }
        const u16* Asr = As + cur * 4096;
        const u16* Bsr = Bs + cur * 4096;
        short8 af[4], bf[4];
#pragma unroll
        for (int i = 0; i < 4; ++i)
            af[i] = *(const short8*)&Asr[(wr * 64 + i * 16 + l16) * 32 + ((quad ^ swz) * 8)];
#pragma unroll
        for (int n = 0; n < 4; ++n)
            bf[n] = *(const short8*)&Bsr[(wc * 64 + n * 16 + l16) * 32 + ((quad ^ swz) * 8)];
#pragma unroll
        for (int i = 0; i < 4; ++i)
#pragma unroll
            for (int n = 0; n < 4; ++n)
                acc[i][n] = __builtin_amdgcn_mfma_f32_16x16x32_bf16(af[i], bf[n], acc[i][n], 0, 0, 0);
        __syncthreads();                   // next tile landed + this buf free
        cur ^= 1;
    }

#pragma unroll
    for (int n = 0; n < 4; ++n) {
        const int col = bn0 + wc * 64 + n * 16 + l16;
        if (col < Nreal) {
            float badd = 0.0f;
            if (BIAS) badd = f ? ((const float*)bias)[col] : bf2f(((const u16*)bias)[col]);
#pragma unroll
            for (int i = 0; i < 4; ++i)
#pragma unroll
                for (int r = 0; r < 4; ++r) {
                    const int row = bm0 + wr * 64 + i * 16 + quad * 4 + r;
                    const float val = acc[i][n][r] + badd;
                    if (OUT_DYN && f) ((float*)C)[(size_t)row * Nreal + col] = val;
                    else              ((u16*)C)[(size_t)row * Nreal + col] = f2bf(val);
                }
        }
    }
}

// ---------------------------------------------------------------------------
// Fused q/k/v projection GEMMs in ONE launch, kv roles dispatched first.
// ---------------------------------------------------------------------------
struct GemmRoles {
    const u16* A[3]; const u16* B[3]; u16* C[3];
    int mblk[3]; int kdim[3]; int start[3];
};

__global__ __launch_bounds__(256) void gemm_qkv(GemmRoles g) {
    __shared__ __align__(16) u16 As[2 * 128 * 32];
    __shared__ __align__(16) u16 Bs[2 * 128 * 32];
    const int id = blockIdx.x;
    const int role = (id >= g.start[1]) + (id >= g.start[2]);
    const int rid = id - g.start[role];
    const int mb = g.mblk[role];
    const int bx = rid % mb, by = rid / mb;
    gemm_body<false, false>(g.A[role], g.B[role], nullptr, g.C[role],
                            bx, by, NINNER, g.kdim[role], 0, As, Bs);
}

__global__ __launch_bounds__(256) void gemm_out(const u16* __restrict__ A,
                                                const u16* __restrict__ B,
                                                const void* __restrict__ bias,
                                                void* __restrict__ C,
                                                const int* __restrict__ flag) {
    __shared__ __align__(16) u16 As[2 * 128 * 32];
    __shared__ __align__(16) u16 Bs[2 * 128 * 32];
    const int f = *flag;
    gemm_body<true, true>(A, B, bias, C, blockIdx.x, blockIdx.y, NQD, NINNER, f, As, Bs);
}

// ---------------------------------------------------------------------------
// V transpose into (b,h,c,m) with K padded 80->96 (zeros). Internal bf16.
// ---------------------------------------------------------------------------
__global__ __launch_bounds__(256) void transpose_v(const u16* __restrict__ v,
                                                   u16* __restrict__ vT) {
    int b = blockIdx.x >> 3, h = blockIdx.x & 7;
    const u16* src = v + (size_t)b * NM * NINNER + h * NC;
    u16* o = vT + (size_t)(b * NH + h) * NC * 96;
    for (int idx = threadIdx.x; idx < NM * NC; idx += 256) {
        int m = idx >> 6, c = idx & 63;
        o[c * 96 + m] = src[(size_t)m * NINNER + c];
    }
    for (int idx = threadIdx.x; idx < NC * 16; idx += 256) {
        int c = idx >> 4, m = 80 + (idx & 15);
        o[c * 96 + m] = 0;
    }
}

// ---------------------------------------------------------------------------
// Fused attention, swapped-QK layout (lane = q-row). EXACT round-4-passing
// body with ONE change: __launch_bounds__(256, 4) caps waves/EU at 4 ->
// VGPR budget 128 (was 60 at max-occupancy target), so the prefetched
// qa/kf/bias/vf live set stays in registers instead of being re-serialized.
// Single-variable A/B vs the 324.78us run.
// ---------------------------------------------------------------------------
__global__ __launch_bounds__(256, 4) void attn_kernel(const u16* __restrict__ q,
                                                      const u16* __restrict__ k,
                                                      const u16* __restrict__ vT,
                                                      const float* __restrict__ maskbias,
                                                      const void* __restrict__ box,
                                                      const void* __restrict__ road,
                                                      u16* __restrict__ attno,
                                                      const int* __restrict__ flag) {
    const int f = *flag;
    const int n0 = blockIdx.x * 64;
    const int h = blockIdx.y;
    const int b = blockIdx.z;
    const int tid = threadIdx.x;
    const int wave = tid >> 6, lane = tid & 63;
    const int l16 = lane & 15, quad = lane >> 4;

    __shared__ __align__(16) u16 p_lds[64][104];

    // ---- prefetch phase: q + k + bias inputs all issued up front ----
    const int n = n0 + 16 * wave + l16;             // this lane's q-row
    const size_t qrow = (size_t)(b * NN + n) * NINNER + h * NC;
    short8 qa[2];
    qa[0] = *(const short8*)(q + qrow + 0 + quad * 8);
    qa[1] = *(const short8*)(q + qrow + 32 + quad * 8);
    short8 kf[5][2];
#pragma unroll
    for (int mt = 0; mt < 5; ++mt) {
        const u16* kr = k + (size_t)(b * NM + mt * 16 + l16) * NINNER + h * NC + quad * 8;
        kf[mt][0] = *(const short8*)(kr + 0);
        kf[mt][1] = *(const short8*)(kr + 32);
    }
    // bias inputs: per lane m = 16*mt + quad*4 + r
    const size_t boxbase = ((size_t)b * NN + n) * NM;
    floatx4 bx4[5]; short4v bxh[5]; floatx4 mb4[5];
    float roadf = 0.0f; u16 roadh = 0;
    if (f) {
#pragma unroll
        for (int mt = 0; mt < 5; ++mt)
            bx4[mt] = *(const floatx4*)((const float*)box + boxbase + 16 * mt + 4 * quad);
        roadf = ((const float*)road)[(size_t)b * NN + n];
    } else {
#pragma unroll
        for (int mt = 0; mt < 5; ++mt)
            bxh[mt] = *(const short4v*)((const u16*)box + boxbase + 16 * mt + 4 * quad);
        roadh = ((const u16*)road)[(size_t)b * NN + n];
    }
#pragma unroll
    for (int mt = 0; mt < 5; ++mt)
        mb4[mt] = *(const floatx4*)(maskbias + b * NM + 16 * mt + 4 * quad);

    // ---- QK^T, swapped operands: D[row=m][col=q-row] ----
    floatx4 s[5];
#pragma unroll
    for (int i = 0; i < 5; ++i) s[i] = (floatx4)0.0f;
#pragma unroll
    for (int kk2 = 0; kk2 < 2; ++kk2)
#pragma unroll
        for (int mt = 0; mt < 5; ++mt)
            s[mt] = __builtin_amdgcn_mfma_f32_16x16x32_bf16(kf[mt][kk2], qa[kk2], s[mt], 0, 0, 0);

    // ---- V fragment prefetch (fills registers freed by kf; latency hides
    //      under bias+softmax VALU chain) ----
    const u16* vbase = vT + (size_t)(b * NH + h) * NC * 96;
    short8 vf[3][4];
#pragma unroll
    for (int kt = 0; kt < 3; ++kt)
#pragma unroll
        for (int nt = 0; nt < 4; ++nt)
            vf[kt][nt] = *(const short8*)(vbase + (size_t)(nt * 16 + l16) * 96 + kt * 32 + quad * 8);

    // ---- combined bias ----
    const float roadv = 5.0f * (f ? roadf : bf2f(roadh));
    floatx4 cb[5];
#pragma unroll
    for (int mt = 0; mt < 5; ++mt)
#pragma unroll
        for (int r = 0; r < 4; ++r) {
            const float boxv = f ? bx4[mt][r] : bf2f((u16)bxh[mt][r]);
            cb[mt][r] = mb4[mt][r] + 5.0f * boxv + roadv;
        }

    // ---- post-MFMA: one fma per element ----
#pragma unroll
    for (int mt = 0; mt < 5; ++mt)
#pragma unroll
        for (int r = 0; r < 4; ++r)
            s[mt][r] = s[mt][r] * 0.125f + cb[mt][r];

    // ---- softmax over the 80 m-values of this lane's q-row ----
    float mx;
    {
        float t0 = fmaxf(fmaxf(s[0][0], s[0][1]), fmaxf(s[0][2], s[0][3]));
        float t1 = fmaxf(fmaxf(s[1][0], s[1][1]), fmaxf(s[1][2], s[1][3]));
        float t2 = fmaxf(fmaxf(s[2][0], s[2][1]), fmaxf(s[2][2], s[2][3]));
        float t3 = fmaxf(fmaxf(s[3][0], s[3][1]), fmaxf(s[3][2], s[3][3]));
        float t4 = fmaxf(fmaxf(s[4][0], s[4][1]), fmaxf(s[4][2], s[4][3]));
        mx = fmaxf(fmaxf(fmaxf(t0, t1), fmaxf(t2, t3)), t4);
    }
    mx = fmaxf(mx, __shfl_xor(mx, 16));
    mx = fmaxf(mx, __shfl_xor(mx, 32));
    float sum = 0.0f;
#pragma unroll
    for (int mt = 0; mt < 5; ++mt)
#pragma unroll
        for (int r = 0; r < 4; ++r) {
            const float p = __expf(s[mt][r] - mx);
            s[mt][r] = p;
            sum += p;
        }
    sum += __shfl_xor(sum, 16);
    sum += __shfl_xor(sum, 32);
    const float inv = 1.0f / sum;

    // ---- normalized P -> LDS (packed cvt_pk + 8B writes, wave-local) ----
#pragma unroll
    for (int mt = 0; mt < 5; ++mt) {
        uint2v pk;
        pk[0] = cvt_pk_bf16(s[mt][0] * inv, s[mt][1] * inv);
        pk[1] = cvt_pk_bf16(s[mt][2] * inv, s[mt][3] * inv);
        *(uint2v*)&p_lds[16 * wave + l16][16 * mt + 4 * quad] = pk;
    }
    if (quad < 2) *(short8*)&p_lds[16 * wave + l16][80 + 8 * quad] = (short8)0;
    // wave-local handoff: this wave's ds_writes land before its own ds_reads.
    asm volatile("s_waitcnt lgkmcnt(0)" ::: "memory");
    __builtin_amdgcn_sched_barrier(0);

    // ---- PV (B-operands already in registers) ----
    floatx4 o[4];
#pragma unroll
    for (int i = 0; i < 4; ++i) o[i] = (floatx4)0.0f;
#pragma unroll
    for (int kt = 0; kt < 3; ++kt) {
        short8 a = *(const short8*)&p_lds[16 * wave + l16][kt * 32 + quad * 8];
#pragma unroll
        for (int nt = 0; nt < 4; ++nt)
            o[nt] = __builtin_amdgcn_mfma_f32_16x16x32_bf16(a, vf[kt][nt], o[nt], 0, 0, 0);
    }

#pragma unroll
    for (int nt = 0; nt < 4; ++nt) {
#pragma unroll
        for (int r = 0; r < 4; ++r) {
            int nr = n0 + 16 * wave + quad * 4 + r;
            attno[((size_t)b * NN + nr) * NINNER + h * NC + nt * 16 + l16] = f2bf(o[nt][r]);
        }
    }
}

extern "C" void kernel_launch(void* const* d_in, const int* in_sizes, int n_in,
                              void* d_out, int out_size, void* d_ws, size_t ws_size,
                              hipStream_t stream) {
    (void)in_sizes; (void)n_in; (void)out_size; (void)ws_size;
    const void* x    = d_in[0];
    const void* key  = d_in[1];
    const void* val  = d_in[2];
    const unsigned char* mask = (const unsigned char*)d_in[3];
    const void* box  = d_in[4];
    const void* road = d_in[5];
    const void* Wq   = d_in[6];
    const void* Wk   = d_in[7];
    const void* Wv   = d_in[8];
    const void* Wo   = d_in[9];
    const void* bo   = d_in[10];

    char* ws = (char*)d_ws;
    size_t off = 0;
    auto carve = [&](size_t bytes) {
        char* p = ws + off;
        off += (bytes + 255) & ~(size_t)255;
        return p;
    };
    int* flag   = (int*)carve(256);
    u16* q_ws   = (u16*)carve((size_t)NB * NN * NINNER * 2);   // 50.3 MB
    u16* k_ws   = (u16*)carve((size_t)NB * NM * NINNER * 2);   // 2.6 MB
    u16* v_ws   = (u16*)carve((size_t)NB * NM * NINNER * 2);   // 2.6 MB
    u16* vT_ws  = (u16*)carve((size_t)NB * NH * NC * 96 * 2);  // 3.1 MB
    u16* ao_ws  = (u16*)carve((size_t)NB * NN * NINNER * 2);   // 50.3 MB
    u16* x_bf   = ao_ws;  // alias: x_bf dead before attn writes ao_ws
    u16* key_bf = (u16*)carve((size_t)NB * NM * NKD * 2);      // 3.9 MB
    u16* val_bf = (u16*)carve((size_t)NB * NM * NKD * 2);      // 3.9 MB
    u16* Wq_bf  = (u16*)carve((size_t)NINNER * NQD * 2);
    u16* Wk_bf  = (u16*)carve((size_t)NINNER * NKD * 2);
    u16* Wv_bf  = (u16*)carve((size_t)NINNER * NKD * 2);
    u16* WoP_bf = (u16*)carve((size_t)384 * NINNER * 2);
    float* mb   = (float*)carve((size_t)NB * NM * 4);

    prep<<<2, 256, 0, stream>>>((const u16*)x, mask, flag, mb);

    ConvArgs ca;
    ca.s[0] = { x,     x_bf,   (long)NB * NN * NQD, (long)NB * NN * NQD / 2048 };   // 7680
    ca.s[1] = { key,   key_bf, (long)NB * NM * NKD, (long)NB * NM * NKD / 2048 };   // 960
    ca.s[2] = { val,   val_bf, (long)NB * NM * NKD, (long)NB * NM * NKD / 2048 };   // 960
    ca.s[3] = { Wq,    Wq_bf,  (long)NINNER * NQD,  (long)NINNER * NQD / 2048 };    // 80
    ca.s[4] = { Wk,    Wk_bf,  (long)NINNER * NKD,  (long)NINNER * NKD / 2048 };    // 192
    ca.s[5] = { Wv,    Wv_bf,  (long)NINNER * NKD,  (long)NINNER * NKD / 2048 };    // 192
    ca.s[6] = { Wo,    WoP_bf, (long)NQD * NINNER,  (long)384 * NINNER / 2048 };    // 96 (pad rows 320..383)
    long totblk = 0;
    for (int i = 0; i < 7; ++i) totblk += ca.s[i].nblk;
    conv_batch<<<(int)totblk, 256, 0, stream>>>(ca, flag);

    GemmRoles g;
    g.A[0] = key_bf; g.B[0] = Wk_bf; g.C[0] = k_ws; g.mblk[0] = NB * NM / 128; g.kdim[0] = NKD;
    g.A[1] = val_bf; g.B[1] = Wv_bf; g.C[1] = v_ws; g.mblk[1] = NB * NM / 128; g.kdim[1] = NKD;
    g.A[2] = x_bf;   g.B[2] = Wq_bf; g.C[2] = q_ws; g.mblk[2] = NB * NN / 128; g.kdim[2] = NQD;
    g.start[0] = 0;
    g.start[1] = g.mblk[0] * 4;
    g.start[2] = g.start[1] + g.mblk[1] * 4;
    int gtot = g.start[2] + g.mblk[2] * 4;
    gemm_qkv<<<gtot, 256, 0, stream>>>(g);

    transpose_v<<<NB * NH, 256, 0, stream>>>(v_ws, vT_ws);
    attn_kernel<<<dim3(NN / 64, NH, NB), 256, 0, stream>>>(
        q_ws, k_ws, vT_ws, mb, box, road, ao_ws, flag);
    gemm_out<<<dim3(NB * NN / 128, 384 / 128), 256, 0, stream>>>(
        ao_ws, WoP_bf, bo, d_out, flag);
}

// Round 12
// 298.132 us; speedup vs baseline: 1.0903x; 1.0903x over previous
//
#include <hip/hip_runtime.h>
#include <hip/hip_bf16.h>

typedef __attribute__((ext_vector_type(8))) short short8;
typedef __attribute__((ext_vector_type(4))) short short4v;
typedef __attribute__((ext_vector_type(4))) float floatx4;
typedef __attribute__((ext_vector_type(2))) unsigned uint2v;
typedef unsigned short u16;

#define NB 32
#define NN 1536
#define NM 80
#define NH 8
#define NC 64
#define NINNER 512
#define NQD 320
#define NKD 768

__device__ __forceinline__ float bf2f(u16 u) {
    union { unsigned i; float f; } x; x.i = ((unsigned)u) << 16; return x.f;
}
__device__ __forceinline__ u16 f2bf(float f) {
    unsigned u = __float_as_uint(f);
    unsigned r = (u + 0x7FFFu + ((u >> 16) & 1u)) >> 16;  // RNE
    return (u16)r;
}
// packed f32x2 -> bf16x2, RNE (identical rounding to f2bf)
__device__ __forceinline__ unsigned cvt_pk_bf16(float lo, float hi) {
    unsigned r;
    asm("v_cvt_pk_bf16_f32 %0, %1, %2" : "=v"(r) : "v"(lo), "v"(hi));
    return r;
}
__device__ __forceinline__ short8 cvt8(const float* __restrict__ p) {
    float4 a = ((const float4*)p)[0];
    float4 b = ((const float4*)p)[1];
    short8 r;
    r[0] = (short)f2bf(a.x); r[1] = (short)f2bf(a.y);
    r[2] = (short)f2bf(a.z); r[3] = (short)f2bf(a.w);
    r[4] = (short)f2bf(b.x); r[5] = (short)f2bf(b.y);
    r[6] = (short)f2bf(b.z); r[7] = (short)f2bf(b.w);
    return r;
}
__device__ __forceinline__ void gload16(const u16* g, u16* l) {
    __builtin_amdgcn_global_load_lds(
        (const __attribute__((address_space(1))) unsigned int*)g,
        (__attribute__((address_space(3))) unsigned int*)l, 16, 0, 0);
}

// ---------------------------------------------------------------------------
// prep: block 0 = input dtype detect (flag=1 means f32 inputs), block 1 =
// mask dtype self-detect + additive bias build.
// ---------------------------------------------------------------------------
__global__ __launch_bounds__(256) void prep(const u16* __restrict__ x,
                                            const unsigned char* __restrict__ raw,
                                            int* __restrict__ flag,
                                            float* __restrict__ maskbias) {
    if (blockIdx.x == 0) {
        __shared__ int cnt;
        if (threadIdx.x == 0) cnt = 0;
        __syncthreads();
        int c = 0;
        for (int i = threadIdx.x; i < 8192; i += 256) {
            unsigned e = (x[i] >> 7) & 0xFF;
            if (e >= 0xA0) c++;
        }
        atomicAdd(&cnt, c);
        __syncthreads();
        if (threadIdx.x == 0) *flag = (cnt > 64) ? 1 : 0;
    } else {
        __shared__ int c_bf, c_f32, c_u8;
        if (threadIdx.x == 0) { c_bf = 0; c_f32 = 0; c_u8 = 0; }
        __syncthreads();
        for (int i = threadIdx.x; i < NB * NM; i += 256) {
            unsigned char v = raw[i];
            if (v == 0x3F && (i & 3) == 1) atomicAdd(&c_bf, 1);
            if (v == 0x3F && (i & 3) == 3) atomicAdd(&c_f32, 1);
            if (v != 0 && (i & 3) != 0) atomicAdd(&c_u8, 1);
        }
        __syncthreads();
        int md;
        if (c_bf > 0) md = 2;
        else if (c_f32 > 0) md = 3;
        else if (c_u8 > 0) md = 1;
        else md = 0;
        for (int i = threadIdx.x; i < NB * NM; i += 256) {
            bool on;
            if (md == 2) on = ((const u16*)raw)[i] != 0;
            else if (md == 3) on = ((const float*)raw)[i] != 0.0f;
            else if (md == 1) on = raw[i] != 0;
            else on = ((const int*)raw)[i] != 0;
            maskbias[i] = on ? 0.0f : -3.4028234663852886e38f;
        }
    }
}

// ---------------------------------------------------------------------------
// Batched f32->bf16 conversion (or u16 copy when flag=0). Seg 6 is the Wo
// pad: elements >= nreal are written as zeros (rows 320..383).
// ---------------------------------------------------------------------------
struct ConvSeg { const void* src; u16* dst; long nreal; long nblk; };
struct ConvArgs { ConvSeg s[7]; };

__global__ __launch_bounds__(256) void conv_batch(ConvArgs a, const int* __restrict__ flag) {
    const int f = *flag;
    long b = blockIdx.x; int seg = 0;
    while (seg < 7 && b >= a.s[seg].nblk) { b -= a.s[seg].nblk; seg++; }
    if (seg >= 7) return;
    const long idx = b * 2048 + threadIdx.x * 8;
    u16* dst = a.s[seg].dst;
    if (idx >= a.s[seg].nreal) { *(short8*)(dst + idx) = (short8)0; return; }
    if (f) *(short8*)(dst + idx) = cvt8((const float*)a.s[seg].src + idx);
    else   *(short8*)(dst + idx) = *(const short8*)((const u16*)a.s[seg].src + idx);
}

// ---------------------------------------------------------------------------
// bf16 MFMA GEMM body, 2-PHASE double-buffered: stage tile t+1 into buf^1
// BEFORE computing tile t from buf, ONE barrier per K-step. 128x128 tile,
// BK=32, 4 waves in 2x2. LDS 2x(A,B) = 32 KiB.  (unchanged)
// ---------------------------------------------------------------------------
template <bool OUT_DYN, bool BIAS>
__device__ __forceinline__ void gemm_body(const u16* __restrict__ A,
                                          const u16* __restrict__ B,
                                          const void* __restrict__ bias,
                                          void* __restrict__ C,
                                          int bx, int by, int Nreal, int K, int f,
                                          u16* As, u16* Bs) {
    const int tid = threadIdx.x;
    const int wave = tid >> 6, lane = tid & 63;
    const int l16 = lane & 15, quad = lane >> 4;
    const int wr = wave >> 1, wc = wave & 1;
    const int bm0 = bx * 128, bn0 = by * 128;

    const int r0 = tid >> 2, c0 = tid & 3;
    const int sc = c0 ^ ((r0 >> 1) & 3);            // swizzled source chunk
    const u16* Ag = A + (size_t)(bm0 + r0) * K + sc * 8;
    const u16* Bg = B + (size_t)(bn0 + r0) * K + sc * 8;

    const int swz = (l16 >> 1) & 3;                 // read-side chunk swizzle
    floatx4 acc[4][4];
#pragma unroll
    for (int i = 0; i < 4; ++i)
#pragma unroll
        for (int n = 0; n < 4; ++n) acc[i][n] = (floatx4)0.0f;

    // prologue: stage K-tile 0 into buffer 0
    {
        u16* AsW = As + wave * 512;
        u16* BsW = Bs + wave * 512;
        gload16(Ag, AsW);                  gload16(Ag + (size_t)64 * K, AsW + 2048);
        gload16(Bg, BsW);                  gload16(Bg + (size_t)64 * K, BsW + 2048);
    }
    __syncthreads();                       // implicit vmcnt(0): tile 0 landed

    int cur = 0;
    for (int kk = 0; kk < K; kk += 32) {
        if (kk + 32 < K) {                 // stage NEXT tile into other buffer
            u16* AsW = As + (cur ^ 1) * 4096 + wave * 512;
            u16* BsW = Bs + (cur ^ 1) * 4096 + wave * 512;
            gload16(Ag + kk + 32, AsW);
            gload16(Ag + (size_t)64 * K + kk + 32, AsW + 2048);
            gload16(Bg + kk + 32, BsW);
            gload16(Bg + (size_t)64 * K + kk + 32, BsW + 2048);
        }
        const u16* Asr = As + cur * 4096;
        const u16* Bsr = Bs + cur * 4096;
        short8 af[4], bf[4];
#pragma unroll
        for (int i = 0; i < 4; ++i)
            af[i] = *(const short8*)&Asr[(wr * 64 + i * 16 + l16) * 32 + ((quad ^ swz) * 8)];
#pragma unroll
        for (int n = 0; n < 4; ++n)
            bf[n] = *(const short8*)&Bsr[(wc * 64 + n * 16 + l16) * 32 + ((quad ^ swz) * 8)];
#pragma unroll
        for (int i = 0; i < 4; ++i)
#pragma unroll
            for (int n = 0; n < 4; ++n)
                acc[i][n] = __builtin_amdgcn_mfma_f32_16x16x32_bf16(af[i], bf[n], acc[i][n], 0, 0, 0);
        __syncthreads();                   // next tile landed + this buf free
        cur ^= 1;
    }

#pragma unroll
    for (int n = 0; n < 4; ++n) {
        const int col = bn0 + wc * 64 + n * 16 + l16;
        if (col < Nreal) {
            float badd = 0.0f;
            if (BIAS) badd = f ? ((const float*)bias)[col] : bf2f(((const u16*)bias)[col]);
#pragma unroll
            for (int i = 0; i < 4; ++i)
#pragma unroll
                for (int r = 0; r < 4; ++r) {
                    const int row = bm0 + wr * 64 + i * 16 + quad * 4 + r;
                    const float val = acc[i][n][r] + badd;
                    if (OUT_DYN && f) ((float*)C)[(size_t)row * Nreal + col] = val;
                    else              ((u16*)C)[(size_t)row * Nreal + col] = f2bf(val);
                }
        }
    }
}

// ---------------------------------------------------------------------------
// Fused q/k/v projection GEMMs in ONE launch, kv roles dispatched first.
// ---------------------------------------------------------------------------
struct GemmRoles {
    const u16* A[3]; const u16* B[3]; u16* C[3];
    int mblk[3]; int kdim[3]; int start[3];
};

__global__ __launch_bounds__(256) void gemm_qkv(GemmRoles g) {
    __shared__ __align__(16) u16 As[2 * 128 * 32];
    __shared__ __align__(16) u16 Bs[2 * 128 * 32];
    const int id = blockIdx.x;
    const int role = (id >= g.start[1]) + (id >= g.start[2]);
    const int rid = id - g.start[role];
    const int mb = g.mblk[role];
    const int bx = rid % mb, by = rid / mb;
    gemm_body<false, false>(g.A[role], g.B[role], nullptr, g.C[role],
                            bx, by, NINNER, g.kdim[role], 0, As, Bs);
}

__global__ __launch_bounds__(256) void gemm_out(const u16* __restrict__ A,
                                                const u16* __restrict__ B,
                                                const void* __restrict__ bias,
                                                void* __restrict__ C,
                                                const int* __restrict__ flag) {
    __shared__ __align__(16) u16 As[2 * 128 * 32];
    __shared__ __align__(16) u16 Bs[2 * 128 * 32];
    const int f = *flag;
    gemm_body<true, true>(A, B, bias, C, blockIdx.x, blockIdx.y, NQD, NINNER, f, As, Bs);
}

// ---------------------------------------------------------------------------
// V transpose into (b,h,c,m') with row stride 128 and the m-chunk swizzle
// PRE-BAKED: position (c, P) holds m-chunk P ^ (c&7). Rows m>=80 zero.
// attn then stages this buffer into LDS with a LINEAR copy (global_load_lds
// constraint) and reads with the same XOR -> conflict-reduced ds_read_b128.
// ---------------------------------------------------------------------------
__global__ __launch_bounds__(256) void transpose_v(const u16* __restrict__ v,
                                                   u16* __restrict__ vT) {
    int b = blockIdx.x >> 3, h = blockIdx.x & 7;
    const u16* src = v + (size_t)b * NM * NINNER + h * NC;
    u16* o = vT + (size_t)(b * NH + h) * NC * 128;
    for (int idx = threadIdx.x; idx < NC * 128; idx += 256) {
        int c = idx >> 7, m = idx & 127;
        u16 val = (m < NM) ? src[(size_t)m * NINNER + c] : (u16)0;
        o[c * 128 + ((((m >> 3) ^ (c & 7))) << 3) + (m & 7)] = val;
    }
}

// ---------------------------------------------------------------------------
// Fused attention, swapped-QK layout (lane = q-row). K and V staged into LDS
// via global_load_lds (async, ZERO VGPR cost) instead of ~22 per-lane global
// loads that the register allocator serialized (VGPR=52 despite launch_bounds
// headroom, R9 measurement). K source is chunk-XOR swizzled (rule-21
// pattern); V swizzle is pre-baked by transpose_v so staging is linear.
// Per-lane global loads: 13 (qa + bias). One unconditional __syncthreads()
// after staging; the verified wave-local p_lds handoff is unchanged.
// ---------------------------------------------------------------------------
__global__ __launch_bounds__(256) void attn_kernel(const u16* __restrict__ q,
                                                   const u16* __restrict__ k,
                                                   const u16* __restrict__ vT,
                                                   const float* __restrict__ maskbias,
                                                   const void* __restrict__ box,
                                                   const void* __restrict__ road,
                                                   u16* __restrict__ attno,
                                                   const int* __restrict__ flag) {
    const int f = *flag;
    const int n0 = blockIdx.x * 64;
    const int h = blockIdx.y;
    const int b = blockIdx.z;
    const int tid = threadIdx.x;
    const int wave = tid >> 6, lane = tid & 63;
    const int l16 = lane & 15, quad = lane >> 4;

    __shared__ __align__(16) u16 K_lds[80 * 64];    // 10240 B, row = 64 u16
    __shared__ __align__(16) u16 V_lds[64 * 128];   // 16384 B, row = 128 u16
    __shared__ __align__(16) u16 p_lds[64][104];    // 13312 B

    // ---- async K/V staging (no VGPR destinations) ----
    // K: row = tid/8 (+32/issue), LDS linear, SOURCE chunk swizzled so the
    // swizzled read below fetches the right data (XOR involution).
    {
        const int row0 = tid >> 3;
        const int cswz = (tid & 7) ^ (row0 & 7);    // (row&7) invariant across issues (+32)
        const u16* kg = k + ((size_t)b * NM + row0) * NINNER + h * NC + cswz * 8;
        u16* kw = K_lds + wave * 512;
        gload16(kg, kw);
        gload16(kg + (size_t)32 * NINNER, kw + 2048);
        if (wave < 2)
            gload16(kg + (size_t)64 * NINNER, kw + 4096);
    }
    // V: pure linear copy (swizzle pre-baked in vT layout).
    {
        const u16* vg = vT + (size_t)(b * NH + h) * NC * 128 + tid * 8;
        u16* vw = V_lds + wave * 512;
#pragma unroll
        for (int i = 0; i < 4; ++i)
            gload16(vg + i * 2048, vw + i * 2048);
    }

    // ---- per-lane global loads: q-row + bias inputs (13 total) ----
    const int n = n0 + 16 * wave + l16;             // this lane's q-row
    const size_t qrow = (size_t)(b * NN + n) * NINNER + h * NC;
    short8 qa[2];
    qa[0] = *(const short8*)(q + qrow + 0 + quad * 8);
    qa[1] = *(const short8*)(q + qrow + 32 + quad * 8);
    const size_t boxbase = ((size_t)b * NN + n) * NM;
    floatx4 bx4[5]; short4v bxh[5]; floatx4 mb4[5];
    float roadf = 0.0f; u16 roadh = 0;
    if (f) {
#pragma unroll
        for (int mt = 0; mt < 5; ++mt)
            bx4[mt] = *(const floatx4*)((const float*)box + boxbase + 16 * mt + 4 * quad);
        roadf = ((const float*)road)[(size_t)b * NN + n];
    } else {
#pragma unroll
        for (int mt = 0; mt < 5; ++mt)
            bxh[mt] = *(const short4v*)((const u16*)box + boxbase + 16 * mt + 4 * quad);
        roadh = ((const u16*)road)[(size_t)b * NN + n];
    }
#pragma unroll
    for (int mt = 0; mt < 5; ++mt)
        mb4[mt] = *(const floatx4*)(maskbias + b * NM + 16 * mt + 4 * quad);

    // ---- combined bias (frees the bias registers before the MFMA phase) ----
    const float roadv = 5.0f * (f ? roadf : bf2f(roadh));
    floatx4 cb[5];
#pragma unroll
    for (int mt = 0; mt < 5; ++mt)
#pragma unroll
        for (int r = 0; r < 4; ++r) {
            const float boxv = f ? bx4[mt][r] : bf2f((u16)bxh[mt][r]);
            cb[mt][r] = mb4[mt][r] + 5.0f * boxv + roadv;
        }

    __syncthreads();                                // drains vmcnt: K/V landed

    // ---- QK^T from LDS, swapped operands: D[row=m][col=q-row] ----
    const int rsw = l16 & 7;                        // read-side chunk swizzle
    floatx4 s[5];
#pragma unroll
    for (int i = 0; i < 5; ++i) s[i] = (floatx4)0.0f;
#pragma unroll
    for (int kk2 = 0; kk2 < 2; ++kk2)
#pragma unroll
        for (int mt = 0; mt < 5; ++mt) {
            short8 kfr = *(const short8*)&K_lds[(mt * 16 + l16) * 64 + (((kk2 * 4 + quad) ^ rsw) * 8)];
            s[mt] = __builtin_amdgcn_mfma_f32_16x16x32_bf16(kfr, qa[kk2], s[mt], 0, 0, 0);
        }

    // ---- post-MFMA: one fma per element ----
#pragma unroll
    for (int mt = 0; mt < 5; ++mt)
#pragma unroll
        for (int r = 0; r < 4; ++r)
            s[mt][r] = s[mt][r] * 0.125f + cb[mt][r];

    // ---- softmax over the 80 m-values of this lane's q-row ----
    float mx;
    {
        float t0 = fmaxf(fmaxf(s[0][0], s[0][1]), fmaxf(s[0][2], s[0][3]));
        float t1 = fmaxf(fmaxf(s[1][0], s[1][1]), fmaxf(s[1][2], s[1][3]));
        float t2 = fmaxf(fmaxf(s[2][0], s[2][1]), fmaxf(s[2][2], s[2][3]));
        float t3 = fmaxf(fmaxf(s[3][0], s[3][1]), fmaxf(s[3][2], s[3][3]));
        float t4 = fmaxf(fmaxf(s[4][0], s[4][1]), fmaxf(s[4][2], s[4][3]));
        mx = fmaxf(fmaxf(fmaxf(t0, t1), fmaxf(t2, t3)), t4);
    }
    mx = fmaxf(mx, __shfl_xor(mx, 16));
    mx = fmaxf(mx, __shfl_xor(mx, 32));
    float sum = 0.0f;
#pragma unroll
    for (int mt = 0; mt < 5; ++mt)
#pragma unroll
        for (int r = 0; r < 4; ++r) {
            const float p = __expf(s[mt][r] - mx);
            s[mt][r] = p;
            sum += p;
        }
    sum += __shfl_xor(sum, 16);
    sum += __shfl_xor(sum, 32);
    const float inv = 1.0f / sum;

    // ---- normalized P -> LDS (packed cvt_pk + 8B writes, wave-local) ----
#pragma unroll
    for (int mt = 0; mt < 5; ++mt) {
        uint2v pk;
        pk[0] = cvt_pk_bf16(s[mt][0] * inv, s[mt][1] * inv);
        pk[1] = cvt_pk_bf16(s[mt][2] * inv, s[mt][3] * inv);
        *(uint2v*)&p_lds[16 * wave + l16][16 * mt + 4 * quad] = pk;
    }
    if (quad < 2) *(short8*)&p_lds[16 * wave + l16][80 + 8 * quad] = (short8)0;
    // wave-local handoff: this wave's ds_writes land before its own ds_reads.
    asm volatile("s_waitcnt lgkmcnt(0)" ::: "memory");
    __builtin_amdgcn_sched_barrier(0);

    // ---- PV from LDS (P[*][80..95]=0 makes the V pad rows irrelevant) ----
    floatx4 o[4];
#pragma unroll
    for (int i = 0; i < 4; ++i) o[i] = (floatx4)0.0f;
#pragma unroll
    for (int kt = 0; kt < 3; ++kt) {
        short8 pb = *(const short8*)&p_lds[16 * wave + l16][kt * 32 + quad * 8];
#pragma unroll
        for (int nt = 0; nt < 4; ++nt) {
            short8 vfr = *(const short8*)&V_lds[(nt * 16 + l16) * 128 + (((kt * 4 + quad) ^ rsw) * 8)];
            o[nt] = __builtin_amdgcn_mfma_f32_16x16x32_bf16(pb, vfr, o[nt], 0, 0, 0);
        }
    }

#pragma unroll
    for (int nt = 0; nt < 4; ++nt) {
#pragma unroll
        for (int r = 0; r < 4; ++r) {
            int nr = n0 + 16 * wave + quad * 4 + r;
            attno[((size_t)b * NN + nr) * NINNER + h * NC + nt * 16 + l16] = f2bf(o[nt][r]);
        }
    }
}

extern "C" void kernel_launch(void* const* d_in, const int* in_sizes, int n_in,
                              void* d_out, int out_size, void* d_ws, size_t ws_size,
                              hipStream_t stream) {
    (void)in_sizes; (void)n_in; (void)out_size; (void)ws_size;
    const void* x    = d_in[0];
    const void* key  = d_in[1];
    const void* val  = d_in[2];
    const unsigned char* mask = (const unsigned char*)d_in[3];
    const void* box  = d_in[4];
    const void* road = d_in[5];
    const void* Wq   = d_in[6];
    const void* Wk   = d_in[7];
    const void* Wv   = d_in[8];
    const void* Wo   = d_in[9];
    const void* bo   = d_in[10];

    char* ws = (char*)d_ws;
    size_t off = 0;
    auto carve = [&](size_t bytes) {
        char* p = ws + off;
        off += (bytes + 255) & ~(size_t)255;
        return p;
    };
    int* flag   = (int*)carve(256);
    u16* q_ws   = (u16*)carve((size_t)NB * NN * NINNER * 2);   // 50.3 MB
    u16* k_ws   = (u16*)carve((size_t)NB * NM * NINNER * 2);   // 2.6 MB
    u16* v_ws   = (u16*)carve((size_t)NB * NM * NINNER * 2);   // 2.6 MB
    u16* vT_ws  = (u16*)carve((size_t)NB * NH * NC * 128 * 2); // 4.2 MB (swizzled layout)
    u16* ao_ws  = (u16*)carve((size_t)NB * NN * NINNER * 2);   // 50.3 MB
    u16* x_bf   = ao_ws;  // alias: x_bf dead before attn writes ao_ws
    u16* key_bf = (u16*)carve((size_t)NB * NM * NKD * 2);      // 3.9 MB
    u16* val_bf = (u16*)carve((size_t)NB * NM * NKD * 2);      // 3.9 MB
    u16* Wq_bf  = (u16*)carve((size_t)NINNER * NQD * 2);
    u16* Wk_bf  = (u16*)carve((size_t)NINNER * NKD * 2);
    u16* Wv_bf  = (u16*)carve((size_t)NINNER * NKD * 2);
    u16* WoP_bf = (u16*)carve((size_t)384 * NINNER * 2);
    float* mb   = (float*)carve((size_t)NB * NM * 4);

    prep<<<2, 256, 0, stream>>>((const u16*)x, mask, flag, mb);

    ConvArgs ca;
    ca.s[0] = { x,     x_bf,   (long)NB * NN * NQD, (long)NB * NN * NQD / 2048 };   // 7680
    ca.s[1] = { key,   key_bf, (long)NB * NM * NKD, (long)NB * NM * NKD / 2048 };   // 960
    ca.s[2] = { val,   val_bf, (long)NB * NM * NKD, (long)NB * NM * NKD / 2048 };   // 960
    ca.s[3] = { Wq,    Wq_bf,  (long)NINNER * NQD,  (long)NINNER * NQD / 2048 };    // 80
    ca.s[4] = { Wk,    Wk_bf,  (long)NINNER * NKD,  (long)NINNER * NKD / 2048 };    // 192
    ca.s[5] = { Wv,    Wv_bf,  (long)NINNER * NKD,  (long)NINNER * NKD / 2048 };    // 192
    ca.s[6] = { Wo,    WoP_bf, (long)NQD * NINNER,  (long)384 * NINNER / 2048 };    // 96 (pad rows 320..383)
    long totblk = 0;
    for (int i = 0; i < 7; ++i) totblk += ca.s[i].nblk;
    conv_batch<<<(int)totblk, 256, 0, stream>>>(ca, flag);

    GemmRoles g;
    g.A[0] = key_bf; g.B[0] = Wk_bf; g.C[0] = k_ws; g.mblk[0] = NB * NM / 128; g.kdim[0] = NKD;
    g.A[1] = val_bf; g.B[1] = Wv_bf; g.C[1] = v_ws; g.mblk[1] = NB * NM / 128; g.kdim[1] = NKD;
    g.A[2] = x_bf;   g.B[2] = Wq_bf; g.C[2] = q_ws; g.mblk[2] = NB * NN / 128; g.kdim[2] = NQD;
    g.start[0] = 0;
    g.start[1] = g.mblk[0] * 4;
    g.start[2] = g.start[1] + g.mblk[1] * 4;
    int gtot = g.start[2] + g.mblk[2] * 4;
    gemm_qkv<<<gtot, 256, 0, stream>>>(g);

    transpose_v<<<NB * NH, 256, 0, stream>>>(v_ws, vT_ws);
    attn_kernel<<<dim3(NN / 64, NH, NB), 256, 0, stream>>>(
        q_ws, k_ws, vT_ws, mb, box, road, ao_ws, flag);
    gemm_out<<<dim3(NB * NN / 128, 384 / 128), 256, 0, stream>>>(
        ao_ws, WoP_bf, bo, d_out, flag);
}

// Round 13
// 292.554 us; speedup vs baseline: 1.1111x; 1.0191x over previous
//
#include <hip/hip_runtime.h>
#include <hip/hip_bf16.h>

typedef __attribute__((ext_vector_type(8))) short short8;
typedef __attribute__((ext_vector_type(4))) short short4v;
typedef __attribute__((ext_vector_type(4))) float floatx4;
typedef __attribute__((ext_vector_type(2))) unsigned uint2v;
typedef unsigned short u16;

#define NB 32
#define NN 1536
#define NM 80
#define NH 8
#define NC 64
#define NINNER 512
#define NQD 320
#define NKD 768

__device__ __forceinline__ float bf2f(u16 u) {
    union { unsigned i; float f; } x; x.i = ((unsigned)u) << 16; return x.f;
}
__device__ __forceinline__ u16 f2bf(float f) {
    unsigned u = __float_as_uint(f);
    unsigned r = (u + 0x7FFFu + ((u >> 16) & 1u)) >> 16;  // RNE
    return (u16)r;
}
// packed f32x2 -> bf16x2, RNE (identical rounding to f2bf)
__device__ __forceinline__ unsigned cvt_pk_bf16(float lo, float hi) {
    unsigned r;
    asm("v_cvt_pk_bf16_f32 %0, %1, %2" : "=v"(r) : "v"(lo), "v"(hi));
    return r;
}
__device__ __forceinline__ short8 cvt8(const float* __restrict__ p) {
    float4 a = ((const float4*)p)[0];
    float4 b = ((const float4*)p)[1];
    short8 r;
    r[0] = (short)f2bf(a.x); r[1] = (short)f2bf(a.y);
    r[2] = (short)f2bf(a.z); r[3] = (short)f2bf(a.w);
    r[4] = (short)f2bf(b.x); r[5] = (short)f2bf(b.y);
    r[6] = (short)f2bf(b.z); r[7] = (short)f2bf(b.w);
    return r;
}
__device__ __forceinline__ void gload16(const u16* g, u16* l) {
    __builtin_amdgcn_global_load_lds(
        (const __attribute__((address_space(1))) unsigned int*)g,
        (__attribute__((address_space(3))) unsigned int*)l, 16, 0, 0);
}

// ---------------------------------------------------------------------------
// prep: block 0 = input dtype detect (flag=1 means f32 inputs), block 1 =
// mask dtype self-detect + additive bias build.
// ---------------------------------------------------------------------------
__global__ __launch_bounds__(256) void prep(const u16* __restrict__ x,
                                            const unsigned char* __restrict__ raw,
                                            int* __restrict__ flag,
                                            float* __restrict__ maskbias) {
    if (blockIdx.x == 0) {
        __shared__ int cnt;
        if (threadIdx.x == 0) cnt = 0;
        __syncthreads();
        int c = 0;
        for (int i = threadIdx.x; i < 8192; i += 256) {
            unsigned e = (x[i] >> 7) & 0xFF;
            if (e >= 0xA0) c++;
        }
        atomicAdd(&cnt, c);
        __syncthreads();
        if (threadIdx.x == 0) *flag = (cnt > 64) ? 1 : 0;
    } else {
        __shared__ int c_bf, c_f32, c_u8;
        if (threadIdx.x == 0) { c_bf = 0; c_f32 = 0; c_u8 = 0; }
        __syncthreads();
        for (int i = threadIdx.x; i < NB * NM; i += 256) {
            unsigned char v = raw[i];
            if (v == 0x3F && (i & 3) == 1) atomicAdd(&c_bf, 1);
            if (v == 0x3F && (i & 3) == 3) atomicAdd(&c_f32, 1);
            if (v != 0 && (i & 3) != 0) atomicAdd(&c_u8, 1);
        }
        __syncthreads();
        int md;
        if (c_bf > 0) md = 2;
        else if (c_f32 > 0) md = 3;
        else if (c_u8 > 0) md = 1;
        else md = 0;
        for (int i = threadIdx.x; i < NB * NM; i += 256) {
            bool on;
            if (md == 2) on = ((const u16*)raw)[i] != 0;
            else if (md == 3) on = ((const float*)raw)[i] != 0.0f;
            else if (md == 1) on = raw[i] != 0;
            else on = ((const int*)raw)[i] != 0;
            maskbias[i] = on ? 0.0f : -3.4028234663852886e38f;
        }
    }
}

// ---------------------------------------------------------------------------
// Batched f32->bf16 conversion (or u16 copy when flag=0). Seg 6 is the Wo
// pad: elements >= nreal are written as zeros (rows 320..383).
// ---------------------------------------------------------------------------
struct ConvSeg { const void* src; u16* dst; long nreal; long nblk; };
struct ConvArgs { ConvSeg s[7]; };

__global__ __launch_bounds__(256) void conv_batch(ConvArgs a, const int* __restrict__ flag) {
    const int f = *flag;
    long b = blockIdx.x; int seg = 0;
    while (seg < 7 && b >= a.s[seg].nblk) { b -= a.s[seg].nblk; seg++; }
    if (seg >= 7) return;
    const long idx = b * 2048 + threadIdx.x * 8;
    u16* dst = a.s[seg].dst;
    if (idx >= a.s[seg].nreal) { *(short8*)(dst + idx) = (short8)0; return; }
    if (f) *(short8*)(dst + idx) = cvt8((const float*)a.s[seg].src + idx);
    else   *(short8*)(dst + idx) = *(const short8*)((const u16*)a.s[seg].src + idx);
}

// ---------------------------------------------------------------------------
// bf16 MFMA GEMM body, 3-BUFFER counted-vmcnt pipeline (catalog T4): stage
// tile t+2 while computing tile t; raw s_barrier + s_waitcnt vmcnt(4) (never
// 0 in steady state) so prefetch loads stay in flight ACROSS barriers --
// replaces __syncthreads()'s full vmcnt(0) drain that exposed ~500+ cy of
// HBM latency per K-step (R12: gemm_out 50us at 14% MfmaUtil / 34% HBM).
// WAR safety: buf (t+2)%3 was last ds_read at step t-1; those reads are
// register-consumed (lgkmcnt-forced by MFMA use) before that wave's step-t
// barrier, so post-barrier staging cannot race them. 128x128 tile, BK=32,
// 4 waves 2x2. LDS 3x(A,B) = 48 KiB -> 3 blocks/CU.
// ---------------------------------------------------------------------------
template <bool OUT_DYN, bool BIAS>
__device__ __forceinline__ void gemm_body(const u16* __restrict__ A,
                                          const u16* __restrict__ B,
                                          const void* __restrict__ bias,
                                          void* __restrict__ C,
                                          int bx, int by, int Nreal, int K, int f,
                                          u16* As, u16* Bs) {
    const int tid = threadIdx.x;
    const int wave = tid >> 6, lane = tid & 63;
    const int l16 = lane & 15, quad = lane >> 4;
    const int wr = wave >> 1, wc = wave & 1;
    const int bm0 = bx * 128, bn0 = by * 128;

    const int r0 = tid >> 2, c0 = tid & 3;
    const int sc = c0 ^ ((r0 >> 1) & 3);            // swizzled source chunk
    const u16* Ag = A + (size_t)(bm0 + r0) * K + sc * 8;
    const u16* Bg = B + (size_t)(bn0 + r0) * K + sc * 8;

    const int swz = (l16 >> 1) & 3;                 // read-side chunk swizzle
    floatx4 acc[4][4];
#pragma unroll
    for (int i = 0; i < 4; ++i)
#pragma unroll
        for (int n = 0; n < 4; ++n) acc[i][n] = (floatx4)0.0f;

    const int nstep = K >> 5;
    // stage K-tile t (k = t*32) into buffer bi: 4 async loads, no VGPR dest
    auto stage = [&](int t, int bi) {
        u16* AsW = As + bi * 4096 + wave * 512;
        u16* BsW = Bs + bi * 4096 + wave * 512;
        gload16(Ag + t * 32, AsW);
        gload16(Ag + (size_t)64 * K + t * 32, AsW + 2048);
        gload16(Bg + t * 32, BsW);
        gload16(Bg + (size_t)64 * K + t * 32, BsW + 2048);
    };
    stage(0, 0);
    stage(1, 1);

    int buf = 0;
    for (int t = 0; t < nstep; ++t) {
        // wait: this wave's tile-t loads landed (newest 4 = tile t+1 may
        // remain in flight). Last iter has no younger tile -> drain.
        if (t + 1 < nstep) asm volatile("s_waitcnt vmcnt(4)" ::: "memory");
        else               asm volatile("s_waitcnt vmcnt(0)" ::: "memory");
        __builtin_amdgcn_s_barrier();       // all waves' tile-t loads landed
        __builtin_amdgcn_sched_barrier(0);  // pin ds_reads below the wait

        const u16* Asr = As + buf * 4096;
        const u16* Bsr = Bs + buf * 4096;
        short8 af[4], bf[4];
#pragma unroll
        for (int i = 0; i < 4; ++i)
            af[i] = *(const short8*)&Asr[(wr * 64 + i * 16 + l16) * 32 + ((quad ^ swz) * 8)];
#pragma unroll
        for (int n = 0; n < 4; ++n)
            bf[n] = *(const short8*)&Bsr[(wc * 64 + n * 16 + l16) * 32 + ((quad ^ swz) * 8)];

        if (t + 2 < nstep) {                // stage into buf (t+2)%3 = buf-1
            const int bi = (buf == 0) ? 2 : buf - 1;
            stage(t + 2, bi);
        }

#pragma unroll
        for (int i = 0; i < 4; ++i)
#pragma unroll
            for (int n = 0; n < 4; ++n)
                acc[i][n] = __builtin_amdgcn_mfma_f32_16x16x32_bf16(af[i], bf[n], acc[i][n], 0, 0, 0);

        buf = (buf == 2) ? 0 : buf + 1;
    }

#pragma unroll
    for (int n = 0; n < 4; ++n) {
        const int col = bn0 + wc * 64 + n * 16 + l16;
        if (col < Nreal) {
            float badd = 0.0f;
            if (BIAS) badd = f ? ((const float*)bias)[col] : bf2f(((const u16*)bias)[col]);
#pragma unroll
            for (int i = 0; i < 4; ++i)
#pragma unroll
                for (int r = 0; r < 4; ++r) {
                    const int row = bm0 + wr * 64 + i * 16 + quad * 4 + r;
                    const float val = acc[i][n][r] + badd;
                    if (OUT_DYN && f) ((float*)C)[(size_t)row * Nreal + col] = val;
                    else              ((u16*)C)[(size_t)row * Nreal + col] = f2bf(val);
                }
        }
    }
}

// ---------------------------------------------------------------------------
// Fused q/k/v projection GEMMs in ONE launch, kv roles dispatched first.
// ---------------------------------------------------------------------------
struct GemmRoles {
    const u16* A[3]; const u16* B[3]; u16* C[3];
    int mblk[3]; int kdim[3]; int start[3];
};

__global__ __launch_bounds__(256) void gemm_qkv(GemmRoles g) {
    __shared__ __align__(16) u16 As[3 * 128 * 32];
    __shared__ __align__(16) u16 Bs[3 * 128 * 32];
    const int id = blockIdx.x;
    const int role = (id >= g.start[1]) + (id >= g.start[2]);
    const int rid = id - g.start[role];
    const int mb = g.mblk[role];
    const int bx = rid % mb, by = rid / mb;
    gemm_body<false, false>(g.A[role], g.B[role], nullptr, g.C[role],
                            bx, by, NINNER, g.kdim[role], 0, As, Bs);
}

__global__ __launch_bounds__(256) void gemm_out(const u16* __restrict__ A,
                                                const u16* __restrict__ B,
                                                const void* __restrict__ bias,
                                                void* __restrict__ C,
                                                const int* __restrict__ flag) {
    __shared__ __align__(16) u16 As[3 * 128 * 32];
    __shared__ __align__(16) u16 Bs[3 * 128 * 32];
    const int f = *flag;
    gemm_body<true, true>(A, B, bias, C, blockIdx.x, blockIdx.y, NQD, NINNER, f, As, Bs);
}

// ---------------------------------------------------------------------------
// V transpose into (b,h,c,m') with row stride 128 and the m-chunk swizzle
// PRE-BAKED: position (c, P) holds m-chunk P ^ (c&7). Rows m>=80 zero.
// attn then stages this buffer into LDS with a LINEAR copy (global_load_lds
// constraint) and reads with the same XOR -> conflict-reduced ds_read_b128.
// ---------------------------------------------------------------------------
__global__ __launch_bounds__(256) void transpose_v(const u16* __restrict__ v,
                                                   u16* __restrict__ vT) {
    int b = blockIdx.x >> 3, h = blockIdx.x & 7;
    const u16* src = v + (size_t)b * NM * NINNER + h * NC;
    u16* o = vT + (size_t)(b * NH + h) * NC * 128;
    for (int idx = threadIdx.x; idx < NC * 128; idx += 256) {
        int c = idx >> 7, m = idx & 127;
        u16 val = (m < NM) ? src[(size_t)m * NINNER + c] : (u16)0;
        o[c * 128 + ((((m >> 3) ^ (c & 7))) << 3) + (m & 7)] = val;
    }
}

// ---------------------------------------------------------------------------
// Fused attention, swapped-QK layout (lane = q-row). K and V staged into LDS
// via global_load_lds (async, zero VGPR cost). Verified at R12: 325->298us,
// attn dropped out of top-5. Unchanged this round.
// ---------------------------------------------------------------------------
__global__ __launch_bounds__(256) void attn_kernel(const u16* __restrict__ q,
                                                   const u16* __restrict__ k,
                                                   const u16* __restrict__ vT,
                                                   const float* __restrict__ maskbias,
                                                   const void* __restrict__ box,
                                                   const void* __restrict__ road,
                                                   u16* __restrict__ attno,
                                                   const int* __restrict__ flag) {
    const int f = *flag;
    const int n0 = blockIdx.x * 64;
    const int h = blockIdx.y;
    const int b = blockIdx.z;
    const int tid = threadIdx.x;
    const int wave = tid >> 6, lane = tid & 63;
    const int l16 = lane & 15, quad = lane >> 4;

    __shared__ __align__(16) u16 K_lds[80 * 64];    // 10240 B, row = 64 u16
    __shared__ __align__(16) u16 V_lds[64 * 128];   // 16384 B, row = 128 u16
    __shared__ __align__(16) u16 p_lds[64][104];    // 13312 B

    // ---- async K/V staging (no VGPR destinations) ----
    {
        const int row0 = tid >> 3;
        const int cswz = (tid & 7) ^ (row0 & 7);    // (row&7) invariant across issues (+32)
        const u16* kg = k + ((size_t)b * NM + row0) * NINNER + h * NC + cswz * 8;
        u16* kw = K_lds + wave * 512;
        gload16(kg, kw);
        gload16(kg + (size_t)32 * NINNER, kw + 2048);
        if (wave < 2)
            gload16(kg + (size_t)64 * NINNER, kw + 4096);
    }
    {
        const u16* vg = vT + (size_t)(b * NH + h) * NC * 128 + tid * 8;
        u16* vw = V_lds + wave * 512;
#pragma unroll
        for (int i = 0; i < 4; ++i)
            gload16(vg + i * 2048, vw + i * 2048);
    }

    // ---- per-lane global loads: q-row + bias inputs (13 total) ----
    const int n = n0 + 16 * wave + l16;             // this lane's q-row
    const size_t qrow = (size_t)(b * NN + n) * NINNER + h * NC;
    short8 qa[2];
    qa[0] = *(const short8*)(q + qrow + 0 + quad * 8);
    qa[1] = *(const short8*)(q + qrow + 32 + quad * 8);
    const size_t boxbase = ((size_t)b * NN + n) * NM;
    floatx4 bx4[5]; short4v bxh[5]; floatx4 mb4[5];
    float roadf = 0.0f; u16 roadh = 0;
    if (f) {
#pragma unroll
        for (int mt = 0; mt < 5; ++mt)
            bx4[mt] = *(const floatx4*)((const float*)box + boxbase + 16 * mt + 4 * quad);
        roadf = ((const float*)road)[(size_t)b * NN + n];
    } else {
#pragma unroll
        for (int mt = 0; mt < 5; ++mt)
            bxh[mt] = *(const short4v*)((const u16*)box + boxbase + 16 * mt + 4 * quad);
        roadh = ((const u16*)road)[(size_t)b * NN + n];
    }
#pragma unroll
    for (int mt = 0; mt < 5; ++mt)
        mb4[mt] = *(const floatx4*)(maskbias + b * NM + 16 * mt + 4 * quad);

    // ---- combined bias (frees the bias registers before the MFMA phase) ----
    const float roadv = 5.0f * (f ? roadf : bf2f(roadh));
    floatx4 cb[5];
#pragma unroll
    for (int mt = 0; mt < 5; ++mt)
#pragma unroll
        for (int r = 0; r < 4; ++r) {
            const float boxv = f ? bx4[mt][r] : bf2f((u16)bxh[mt][r]);
            cb[mt][r] = mb4[mt][r] + 5.0f * boxv + roadv;
        }

    __syncthreads();                                // drains vmcnt: K/V landed

    // ---- QK^T from LDS, swapped operands: D[row=m][col=q-row] ----
    const int rsw = l16 & 7;                        // read-side chunk swizzle
    floatx4 s[5];
#pragma unroll
    for (int i = 0; i < 5; ++i) s[i] = (floatx4)0.0f;
#pragma unroll
    for (int kk2 = 0; kk2 < 2; ++kk2)
#pragma unroll
        for (int mt = 0; mt < 5; ++mt) {
            short8 kfr = *(const short8*)&K_lds[(mt * 16 + l16) * 64 + (((kk2 * 4 + quad) ^ rsw) * 8)];
            s[mt] = __builtin_amdgcn_mfma_f32_16x16x32_bf16(kfr, qa[kk2], s[mt], 0, 0, 0);
        }

    // ---- post-MFMA: one fma per element ----
#pragma unroll
    for (int mt = 0; mt < 5; ++mt)
#pragma unroll
        for (int r = 0; r < 4; ++r)
            s[mt][r] = s[mt][r] * 0.125f + cb[mt][r];

    // ---- softmax over the 80 m-values of this lane's q-row ----
    float mx;
    {
        float t0 = fmaxf(fmaxf(s[0][0], s[0][1]), fmaxf(s[0][2], s[0][3]));
        float t1 = fmaxf(fmaxf(s[1][0], s[1][1]), fmaxf(s[1][2], s[1][3]));
        float t2 = fmaxf(fmaxf(s[2][0], s[2][1]), fmaxf(s[2][2], s[2][3]));
        float t3 = fmaxf(fmaxf(s[3][0], s[3][1]), fmaxf(s[3][2], s[3][3]));
        float t4 = fmaxf(fmaxf(s[4][0], s[4][1]), fmaxf(s[4][2], s[4][3]));
        mx = fmaxf(fmaxf(fmaxf(t0, t1), fmaxf(t2, t3)), t4);
    }
    mx = fmaxf(mx, __shfl_xor(mx, 16));
    mx = fmaxf(mx, __shfl_xor(mx, 32));
    float sum = 0.0f;
#pragma unroll
    for (int mt = 0; mt < 5; ++mt)
#pragma unroll
        for (int r = 0; r < 4; ++r) {
            const float p = __expf(s[mt][r] - mx);
            s[mt][r] = p;
            sum += p;
        }
    sum += __shfl_xor(sum, 16);
    sum += __shfl_xor(sum, 32);
    const float inv = 1.0f / sum;

    // ---- normalized P -> LDS (packed cvt_pk + 8B writes, wave-local) ----
#pragma unroll
    for (int mt = 0; mt < 5; ++mt) {
        uint2v pk;
        pk[0] = cvt_pk_bf16(s[mt][0] * inv, s[mt][1] * inv);
        pk[1] = cvt_pk_bf16(s[mt][2] * inv, s[mt][3] * inv);
        *(uint2v*)&p_lds[16 * wave + l16][16 * mt + 4 * quad] = pk;
    }
    if (quad < 2) *(short8*)&p_lds[16 * wave + l16][80 + 8 * quad] = (short8)0;
    // wave-local handoff: this wave's ds_writes land before its own ds_reads.
    asm volatile("s_waitcnt lgkmcnt(0)" ::: "memory");
    __builtin_amdgcn_sched_barrier(0);

    // ---- PV from LDS (P[*][80..95]=0 makes the V pad rows irrelevant) ----
    floatx4 o[4];
#pragma unroll
    for (int i = 0; i < 4; ++i) o[i] = (floatx4)0.0f;
#pragma unroll
    for (int kt = 0; kt < 3; ++kt) {
        short8 pb = *(const short8*)&p_lds[16 * wave + l16][kt * 32 + quad * 8];
#pragma unroll
        for (int nt = 0; nt < 4; ++nt) {
            short8 vfr = *(const short8*)&V_lds[(nt * 16 + l16) * 128 + (((kt * 4 + quad) ^ rsw) * 8)];
            o[nt] = __builtin_amdgcn_mfma_f32_16x16x32_bf16(pb, vfr, o[nt], 0, 0, 0);
        }
    }

#pragma unroll
    for (int nt = 0; nt < 4; ++nt) {
#pragma unroll
        for (int r = 0; r < 4; ++r) {
            int nr = n0 + 16 * wave + quad * 4 + r;
            attno[((size_t)b * NN + nr) * NINNER + h * NC + nt * 16 + l16] = f2bf(o[nt][r]);
        }
    }
}

extern "C" void kernel_launch(void* const* d_in, const int* in_sizes, int n_in,
                              void* d_out, int out_size, void* d_ws, size_t ws_size,
                              hipStream_t stream) {
    (void)in_sizes; (void)n_in; (void)out_size; (void)ws_size;
    const void* x    = d_in[0];
    const void* key  = d_in[1];
    const void* val  = d_in[2];
    const unsigned char* mask = (const unsigned char*)d_in[3];
    const void* box  = d_in[4];
    const void* road = d_in[5];
    const void* Wq   = d_in[6];
    const void* Wk   = d_in[7];
    const void* Wv   = d_in[8];
    const void* Wo   = d_in[9];
    const void* bo   = d_in[10];

    char* ws = (char*)d_ws;
    size_t off = 0;
    auto carve = [&](size_t bytes) {
        char* p = ws + off;
        off += (bytes + 255) & ~(size_t)255;
        return p;
    };
    int* flag   = (int*)carve(256);
    u16* q_ws   = (u16*)carve((size_t)NB * NN * NINNER * 2);   // 50.3 MB
    u16* k_ws   = (u16*)carve((size_t)NB * NM * NINNER * 2);   // 2.6 MB
    u16* v_ws   = (u16*)carve((size_t)NB * NM * NINNER * 2);   // 2.6 MB
    u16* vT_ws  = (u16*)carve((size_t)NB * NH * NC * 128 * 2); // 4.2 MB (swizzled layout)
    u16* ao_ws  = (u16*)carve((size_t)NB * NN * NINNER * 2);   // 50.3 MB
    u16* x_bf   = ao_ws;  // alias: x_bf dead before attn writes ao_ws
    u16* key_bf = (u16*)carve((size_t)NB * NM * NKD * 2);      // 3.9 MB
    u16* val_bf = (u16*)carve((size_t)NB * NM * NKD * 2);      // 3.9 MB
    u16* Wq_bf  = (u16*)carve((size_t)NINNER * NQD * 2);
    u16* Wk_bf  = (u16*)carve((size_t)NINNER * NKD * 2);
    u16* Wv_bf  = (u16*)carve((size_t)NINNER * NKD * 2);
    u16* WoP_bf = (u16*)carve((size_t)384 * NINNER * 2);
    float* mb   = (float*)carve((size_t)NB * NM * 4);

    prep<<<2, 256, 0, stream>>>((const u16*)x, mask, flag, mb);

    ConvArgs ca;
    ca.s[0] = { x,     x_bf,   (long)NB * NN * NQD, (long)NB * NN * NQD / 2048 };   // 7680
    ca.s[1] = { key,   key_bf, (long)NB * NM * NKD, (long)NB * NM * NKD / 2048 };   // 960
    ca.s[2] = { val,   val_bf, (long)NB * NM * NKD, (long)NB * NM * NKD / 2048 };   // 960
    ca.s[3] = { Wq,    Wq_bf,  (long)NINNER * NQD,  (long)NINNER * NQD / 2048 };    // 80
    ca.s[4] = { Wk,    Wk_bf,  (long)NINNER * NKD,  (long)NINNER * NKD / 2048 };    // 192
    ca.s[5] = { Wv,    Wv_bf,  (long)NINNER * NKD,  (long)NINNER * NKD / 2048 };    // 192
    ca.s[6] = { Wo,    WoP_bf, (long)NQD * NINNER,  (long)384 * NINNER / 2048 };    // 96 (pad rows 320..383)
    long totblk = 0;
    for (int i = 0; i < 7; ++i) totblk += ca.s[i].nblk;
    conv_batch<<<(int)totblk, 256, 0, stream>>>(ca, flag);

    GemmRoles g;
    g.A[0] = key_bf; g.B[0] = Wk_bf; g.C[0] = k_ws; g.mblk[0] = NB * NM / 128; g.kdim[0] = NKD;
    g.A[1] = val_bf; g.B[1] = Wv_bf; g.C[1] = v_ws; g.mblk[1] = NB * NM / 128; g.kdim[1] = NKD;
    g.A[2] = x_bf;   g.B[2] = Wq_bf; g.C[2] = q_ws; g.mblk[2] = NB * NN / 128; g.kdim[2] = NQD;
    g.start[0] = 0;
    g.start[1] = g.mblk[0] * 4;
    g.start[2] = g.start[1] + g.mblk[1] * 4;
    int gtot = g.start[2] + g.mblk[2] * 4;
    gemm_qkv<<<gtot, 256, 0, stream>>>(g);

    transpose_v<<<NB * NH, 256, 0, stream>>>(v_ws, vT_ws);
    attn_kernel<<<dim3(NN / 64, NH, NB), 256, 0, stream>>>(
        q_ws, k_ws, vT_ws, mb, box, road, ao_ws, flag);
    gemm_out<<<dim3(NB * NN / 128, 384 / 128), 256, 0, stream>>>(
        ao_ws, WoP_bf, bo, d_out, flag);
}

// Round 19
// 290.882 us; speedup vs baseline: 1.1175x; 1.0058x over previous
//
#include <hip/hip_runtime.h>
#include <hip/hip_bf16.h>

typedef __attribute__((ext_vector_type(8))) short short8;
typedef __attribute__((ext_vector_type(4))) short short4v;
typedef __attribute__((ext_vector_type(4))) float floatx4;
typedef __attribute__((ext_vector_type(2))) unsigned uint2v;
typedef unsigned short u16;

#define NB 32
#define NN 1536
#define NM 80
#define NH 8
#define NC 64
#define NINNER 512
#define NQD 320
#define NKD 768

__device__ __forceinline__ float bf2f(u16 u) {
    union { unsigned i; float f; } x; x.i = ((unsigned)u) << 16; return x.f;
}
__device__ __forceinline__ u16 f2bf(float f) {
    unsigned u = __float_as_uint(f);
    unsigned r = (u + 0x7FFFu + ((u >> 16) & 1u)) >> 16;  // RNE
    return (u16)r;
}
// packed f32x2 -> bf16x2, RNE (identical rounding to f2bf)
__device__ __forceinline__ unsigned cvt_pk_bf16(float lo, float hi) {
    unsigned r;
    asm("v_cvt_pk_bf16_f32 %0, %1, %2" : "=v"(r) : "v"(lo), "v"(hi));
    return r;
}
__device__ __forceinline__ short8 cvt8(const float* __restrict__ p) {
    float4 a = ((const float4*)p)[0];
    float4 b = ((const float4*)p)[1];
    short8 r;
    r[0] = (short)f2bf(a.x); r[1] = (short)f2bf(a.y);
    r[2] = (short)f2bf(a.z); r[3] = (short)f2bf(a.w);
    r[4] = (short)f2bf(b.x); r[5] = (short)f2bf(b.y);
    r[6] = (short)f2bf(b.z); r[7] = (short)f2bf(b.w);
    return r;
}
__device__ __forceinline__ void gload16(const u16* g, u16* l) {
    __builtin_amdgcn_global_load_lds(
        (const __attribute__((address_space(1))) unsigned int*)g,
        (__attribute__((address_space(3))) unsigned int*)l, 16, 0, 0);
}

// ---------------------------------------------------------------------------
// prep: block 0 = input dtype detect (flag=1 means f32 inputs), block 1 =
// mask dtype self-detect + additive bias build.
// ---------------------------------------------------------------------------
__global__ __launch_bounds__(256) void prep(const u16* __restrict__ x,
                                            const unsigned char* __restrict__ raw,
                                            int* __restrict__ flag,
                                            float* __restrict__ maskbias) {
    if (blockIdx.x == 0) {
        __shared__ int cnt;
        if (threadIdx.x == 0) cnt = 0;
        __syncthreads();
        int c = 0;
        for (int i = threadIdx.x; i < 8192; i += 256) {
            unsigned e = (x[i] >> 7) & 0xFF;
            if (e >= 0xA0) c++;
        }
        atomicAdd(&cnt, c);
        __syncthreads();
        if (threadIdx.x == 0) *flag = (cnt > 64) ? 1 : 0;
    } else {
        __shared__ int c_bf, c_f32, c_u8;
        if (threadIdx.x == 0) { c_bf = 0; c_f32 = 0; c_u8 = 0; }
        __syncthreads();
        for (int i = threadIdx.x; i < NB * NM; i += 256) {
            unsigned char v = raw[i];
            if (v == 0x3F && (i & 3) == 1) atomicAdd(&c_bf, 1);
            if (v == 0x3F && (i & 3) == 3) atomicAdd(&c_f32, 1);
            if (v != 0 && (i & 3) != 0) atomicAdd(&c_u8, 1);
        }
        __syncthreads();
        int md;
        if (c_bf > 0) md = 2;
        else if (c_f32 > 0) md = 3;
        else if (c_u8 > 0) md = 1;
        else md = 0;
        for (int i = threadIdx.x; i < NB * NM; i += 256) {
            bool on;
            if (md == 2) on = ((const u16*)raw)[i] != 0;
            else if (md == 3) on = ((const float*)raw)[i] != 0.0f;
            else if (md == 1) on = raw[i] != 0;
            else on = ((const int*)raw)[i] != 0;
            maskbias[i] = on ? 0.0f : -3.4028234663852886e38f;
        }
    }
}

// ---------------------------------------------------------------------------
// Batched f32->bf16 conversion (or u16 copy when flag=0). Seg 6 is the Wo
// pad: elements >= nreal are written as zeros (rows 320..383).
// ---------------------------------------------------------------------------
struct ConvSeg { const void* src; u16* dst; long nreal; long nblk; };
struct ConvArgs { ConvSeg s[7]; };

__global__ __launch_bounds__(256) void conv_batch(ConvArgs a, const int* __restrict__ flag) {
    const int f = *flag;
    long b = blockIdx.x; int seg = 0;
    while (seg < 7 && b >= a.s[seg].nblk) { b -= a.s[seg].nblk; seg++; }
    if (seg >= 7) return;
    const long idx = b * 2048 + threadIdx.x * 8;
    u16* dst = a.s[seg].dst;
    if (idx >= a.s[seg].nreal) { *(short8*)(dst + idx) = (short8)0; return; }
    if (f) *(short8*)(dst + idx) = cvt8((const float*)a.s[seg].src + idx);
    else   *(short8*)(dst + idx) = *(const short8*)((const u16*)a.s[seg].src + idx);
}

// ---------------------------------------------------------------------------
// bf16 MFMA GEMM body, 4-BUFFER counted-vmcnt pipeline, prefetch distance 3:
// stage tile t+3 while computing tile t; steady-state s_waitcnt vmcnt(8)
// (tiles t+1,t+2 stay in flight across barriers). R13 measured distance-2 =
// only -8% (cover ~320cy < ~600-900cy HBM latency); distance-3 covers ~480cy
// + 2-block TLP. WAR: buf (t+3)%4 was last ds_read at step t-1; those reads
// are MFMA-consumed before that wave crosses the step-t barrier. 128x128
// tile, BK=32, 4 waves 2x2. LDS 4x(A,B) = 64 KiB -> 2 blocks/CU (measured
// effective occupancy was 1.7 anyway).
// ---------------------------------------------------------------------------
template <bool OUT_DYN, bool BIAS>
__device__ __forceinline__ void gemm_body(const u16* __restrict__ A,
                                          const u16* __restrict__ B,
                                          const void* __restrict__ bias,
                                          void* __restrict__ C,
                                          int bx, int by, int Nreal, int K, int f,
                                          u16* As, u16* Bs) {
    const int tid = threadIdx.x;
    const int wave = tid >> 6, lane = tid & 63;
    const int l16 = lane & 15, quad = lane >> 4;
    const int wr = wave >> 1, wc = wave & 1;
    const int bm0 = bx * 128, bn0 = by * 128;

    const int r0 = tid >> 2, c0 = tid & 3;
    const int sc = c0 ^ ((r0 >> 1) & 3);            // swizzled source chunk
    const u16* Ag = A + (size_t)(bm0 + r0) * K + sc * 8;
    const u16* Bg = B + (size_t)(bn0 + r0) * K + sc * 8;

    const int swz = (l16 >> 1) & 3;                 // read-side chunk swizzle
    floatx4 acc[4][4];
#pragma unroll
    for (int i = 0; i < 4; ++i)
#pragma unroll
        for (int n = 0; n < 4; ++n) acc[i][n] = (floatx4)0.0f;

    const int nstep = K >> 5;
    // stage K-tile t (k = t*32) into buffer bi: 4 async loads, no VGPR dest
    auto stage = [&](int t, int bi) {
        u16* AsW = As + bi * 4096 + wave * 512;
        u16* BsW = Bs + bi * 4096 + wave * 512;
        gload16(Ag + t * 32, AsW);
        gload16(Ag + (size_t)64 * K + t * 32, AsW + 2048);
        gload16(Bg + t * 32, BsW);
        gload16(Bg + (size_t)64 * K + t * 32, BsW + 2048);
    };
    stage(0, 0);
    stage(1, 1);
    stage(2, 2);

    int buf = 0;
    for (int t = 0; t < nstep; ++t) {
        // wait: tile t landed; keep younger tiles (up to 2 x 4 loads) in flight
        if (t + 2 < nstep)      asm volatile("s_waitcnt vmcnt(8)" ::: "memory");
        else if (t + 1 < nstep) asm volatile("s_waitcnt vmcnt(4)" ::: "memory");
        else                    asm volatile("s_waitcnt vmcnt(0)" ::: "memory");
        __builtin_amdgcn_s_barrier();       // all waves' tile-t loads landed
        __builtin_amdgcn_sched_barrier(0);  // pin ds_reads below the wait

        const u16* Asr = As + buf * 4096;
        const u16* Bsr = Bs + buf * 4096;
        short8 af[4], bf[4];
#pragma unroll
        for (int i = 0; i < 4; ++i)
            af[i] = *(const short8*)&Asr[(wr * 64 + i * 16 + l16) * 32 + ((quad ^ swz) * 8)];
#pragma unroll
        for (int n = 0; n < 4; ++n)
            bf[n] = *(const short8*)&Bsr[(wc * 64 + n * 16 + l16) * 32 + ((quad ^ swz) * 8)];

        if (t + 3 < nstep)                  // stage into buf (t+3)%4
            stage(t + 3, (buf + 3) & 3);

#pragma unroll
        for (int i = 0; i < 4; ++i)
#pragma unroll
            for (int n = 0; n < 4; ++n)
                acc[i][n] = __builtin_amdgcn_mfma_f32_16x16x32_bf16(af[i], bf[n], acc[i][n], 0, 0, 0);

        buf = (buf + 1) & 3;
    }

#pragma unroll
    for (int n = 0; n < 4; ++n) {
        const int col = bn0 + wc * 64 + n * 16 + l16;
        if (col < Nreal) {
            float badd = 0.0f;
            if (BIAS) badd = f ? ((const float*)bias)[col] : bf2f(((const u16*)bias)[col]);
#pragma unroll
            for (int i = 0; i < 4; ++i)
#pragma unroll
                for (int r = 0; r < 4; ++r) {
                    const int row = bm0 + wr * 64 + i * 16 + quad * 4 + r;
                    const float val = acc[i][n][r] + badd;
                    if (OUT_DYN && f) ((float*)C)[(size_t)row * Nreal + col] = val;
                    else              ((u16*)C)[(size_t)row * Nreal + col] = f2bf(val);
                }
        }
    }
}

// ---------------------------------------------------------------------------
// Fused q/k/v projection GEMMs in ONE launch, kv roles dispatched first.
// ---------------------------------------------------------------------------
struct GemmRoles {
    const u16* A[3]; const u16* B[3]; u16* C[3];
    int mblk[3]; int kdim[3]; int start[3];
};

__global__ __launch_bounds__(256) void gemm_qkv(GemmRoles g) {
    __shared__ __align__(16) u16 As[4 * 128 * 32];
    __shared__ __align__(16) u16 Bs[4 * 128 * 32];
    const int id = blockIdx.x;
    const int role = (id >= g.start[1]) + (id >= g.start[2]);
    const int rid = id - g.start[role];
    const int mb = g.mblk[role];
    const int bx = rid % mb, by = rid / mb;
    gemm_body<false, false>(g.A[role], g.B[role], nullptr, g.C[role],
                            bx, by, NINNER, g.kdim[role], 0, As, Bs);
}

__global__ __launch_bounds__(256) void gemm_out(const u16* __restrict__ A,
                                                const u16* __restrict__ B,
                                                const void* __restrict__ bias,
                                                void* __restrict__ C,
                                                const int* __restrict__ flag) {
    __shared__ __align__(16) u16 As[4 * 128 * 32];
    __shared__ __align__(16) u16 Bs[4 * 128 * 32];
    const int f = *flag;
    gemm_body<true, true>(A, B, bias, C, blockIdx.x, blockIdx.y, NQD, NINNER, f, As, Bs);
}

// ---------------------------------------------------------------------------
// V transpose into (b,h,c,m') with row stride 128 and the m-chunk swizzle
// PRE-BAKED: position (c, P) holds m-chunk P ^ (c&7). Rows m>=80 zero.
// LDS-tiled two-phase: coalesced 128B row reads -> LDS -> coalesced 256B row
// writes (swizzle resolved on the LDS-read side). Output layout identical to
// R12/R13's verified version; only the access pattern changed (old read side
// was stride-1024B scalar u16 -- fully uncoalesced).
// ---------------------------------------------------------------------------
__global__ __launch_bounds__(256) void transpose_v(const u16* __restrict__ v,
                                                   u16* __restrict__ vT) {
    __shared__ u16 t_lds[80][68];                   // +4 pad: bank spread
    int b = blockIdx.x >> 3, h = blockIdx.x & 7;
    const u16* src = v + (size_t)b * NM * NINNER + h * NC;
    u16* o = vT + (size_t)(b * NH + h) * NC * 128;
    // phase 1: coalesced read (64 consecutive c per m-row)
    for (int idx = threadIdx.x; idx < NM * NC; idx += 256) {
        int m = idx >> 6, c = idx & 63;
        t_lds[m][c] = src[(size_t)m * NINNER + c];
    }
    __syncthreads();
    // phase 2: coalesced write (128 consecutive positions per c-row)
    for (int idx = threadIdx.x; idx < NC * 128; idx += 256) {
        int c = idx >> 7, p = idx & 127;
        int m = (((p >> 3) ^ (c & 7)) << 3) + (p & 7);
        o[c * 128 + p] = (m < NM) ? t_lds[m][c] : (u16)0;
    }
}

// ---------------------------------------------------------------------------
// Fused attention, swapped-QK layout (lane = q-row). K and V staged into LDS
// via global_load_lds (async, zero VGPR cost). Verified at R12/R13.
// Unchanged this round.
// ---------------------------------------------------------------------------
__global__ __launch_bounds__(256) void attn_kernel(const u16* __restrict__ q,
                                                   const u16* __restrict__ k,
                                                   const u16* __restrict__ vT,
                                                   const float* __restrict__ maskbias,
                                                   const void* __restrict__ box,
                                                   const void* __restrict__ road,
                                                   u16* __restrict__ attno,
                                                   const int* __restrict__ flag) {
    const int f = *flag;
    const int n0 = blockIdx.x * 64;
    const int h = blockIdx.y;
    const int b = blockIdx.z;
    const int tid = threadIdx.x;
    const int wave = tid >> 6, lane = tid & 63;
    const int l16 = lane & 15, quad = lane >> 4;

    __shared__ __align__(16) u16 K_lds[80 * 64];    // 10240 B, row = 64 u16
    __shared__ __align__(16) u16 V_lds[64 * 128];   // 16384 B, row = 128 u16
    __shared__ __align__(16) u16 p_lds[64][104];    // 13312 B

    // ---- async K/V staging (no VGPR destinations) ----
    {
        const int row0 = tid >> 3;
        const int cswz = (tid & 7) ^ (row0 & 7);    // (row&7) invariant across issues (+32)
        const u16* kg = k + ((size_t)b * NM + row0) * NINNER + h * NC + cswz * 8;
        u16* kw = K_lds + wave * 512;
        gload16(kg, kw);
        gload16(kg + (size_t)32 * NINNER, kw + 2048);
        if (wave < 2)
            gload16(kg + (size_t)64 * NINNER, kw + 4096);
    }
    {
        const u16* vg = vT + (size_t)(b * NH + h) * NC * 128 + tid * 8;
        u16* vw = V_lds + wave * 512;
#pragma unroll
        for (int i = 0; i < 4; ++i)
            gload16(vg + i * 2048, vw + i * 2048);
    }

    // ---- per-lane global loads: q-row + bias inputs (13 total) ----
    const int n = n0 + 16 * wave + l16;             // this lane's q-row
    const size_t qrow = (size_t)(b * NN + n) * NINNER + h * NC;
    short8 qa[2];
    qa[0] = *(const short8*)(q + qrow + 0 + quad * 8);
    qa[1] = *(const short8*)(q + qrow + 32 + quad * 8);
    const size_t boxbase = ((size_t)b * NN + n) * NM;
    floatx4 bx4[5]; short4v bxh[5]; floatx4 mb4[5];
    float roadf = 0.0f; u16 roadh = 0;
    if (f) {
#pragma unroll
        for (int mt = 0; mt < 5; ++mt)
            bx4[mt] = *(const floatx4*)((const float*)box + boxbase + 16 * mt + 4 * quad);
        roadf = ((const float*)road)[(size_t)b * NN + n];
    } else {
#pragma unroll
        for (int mt = 0; mt < 5; ++mt)
            bxh[mt] = *(const short4v*)((const u16*)box + boxbase + 16 * mt + 4 * quad);
        roadh = ((const u16*)road)[(size_t)b * NN + n];
    }
#pragma unroll
    for (int mt = 0; mt < 5; ++mt)
        mb4[mt] = *(const floatx4*)(maskbias + b * NM + 16 * mt + 4 * quad);

    // ---- combined bias (frees the bias registers before the MFMA phase) ----
    const float roadv = 5.0f * (f ? roadf : bf2f(roadh));
    floatx4 cb[5];
#pragma unroll
    for (int mt = 0; mt < 5; ++mt)
#pragma unroll
        for (int r = 0; r < 4; ++r) {
            const float boxv = f ? bx4[mt][r] : bf2f((u16)bxh[mt][r]);
            cb[mt][r] = mb4[mt][r] + 5.0f * boxv + roadv;
        }

    __syncthreads();                                // drains vmcnt: K/V landed

    // ---- QK^T from LDS, swapped operands: D[row=m][col=q-row] ----
    const int rsw = l16 & 7;                        // read-side chunk swizzle
    floatx4 s[5];
#pragma unroll
    for (int i = 0; i < 5; ++i) s[i] = (floatx4)0.0f;
#pragma unroll
    for (int kk2 = 0; kk2 < 2; ++kk2)
#pragma unroll
        for (int mt = 0; mt < 5; ++mt) {
            short8 kfr = *(const short8*)&K_lds[(mt * 16 + l16) * 64 + (((kk2 * 4 + quad) ^ rsw) * 8)];
            s[mt] = __builtin_amdgcn_mfma_f32_16x16x32_bf16(kfr, qa[kk2], s[mt], 0, 0, 0);
        }

    // ---- post-MFMA: one fma per element ----
#pragma unroll
    for (int mt = 0; mt < 5; ++mt)
#pragma unroll
        for (int r = 0; r < 4; ++r)
            s[mt][r] = s[mt][r] * 0.125f + cb[mt][r];

    // ---- softmax over the 80 m-values of this lane's q-row ----
    float mx;
    {
        float t0 = fmaxf(fmaxf(s[0][0], s[0][1]), fmaxf(s[0][2], s[0][3]));
        float t1 = fmaxf(fmaxf(s[1][0], s[1][1]), fmaxf(s[1][2], s[1][3]));
        float t2 = fmaxf(fmaxf(s[2][0], s[2][1]), fmaxf(s[2][2], s[2][3]));
        float t3 = fmaxf(fmaxf(s[3][0], s[3][1]), fmaxf(s[3][2], s[3][3]));
        float t4 = fmaxf(fmaxf(s[4][0], s[4][1]), fmaxf(s[4][2], s[4][3]));
        mx = fmaxf(fmaxf(fmaxf(t0, t1), fmaxf(t2, t3)), t4);
    }
    mx = fmaxf(mx, __shfl_xor(mx, 16));
    mx = fmaxf(mx, __shfl_xor(mx, 32));
    float sum = 0.0f;
#pragma unroll
    for (int mt = 0; mt < 5; ++mt)
#pragma unroll
        for (int r = 0; r < 4; ++r) {
            const float p = __expf(s[mt][r] - mx);
            s[mt][r] = p;
            sum += p;
        }
    sum += __shfl_xor(sum, 16);
    sum += __shfl_xor(sum, 32);
    const float inv = 1.0f / sum;

    // ---- normalized P -> LDS (packed cvt_pk + 8B writes, wave-local) ----
#pragma unroll
    for (int mt = 0; mt < 5; ++mt) {
        uint2v pk;
        pk[0] = cvt_pk_bf16(s[mt][0] * inv, s[mt][1] * inv);
        pk[1] = cvt_pk_bf16(s[mt][2] * inv, s[mt][3] * inv);
        *(uint2v*)&p_lds[16 * wave + l16][16 * mt + 4 * quad] = pk;
    }
    if (quad < 2) *(short8*)&p_lds[16 * wave + l16][80 + 8 * quad] = (short8)0;
    // wave-local handoff: this wave's ds_writes land before its own ds_reads.
    asm volatile("s_waitcnt lgkmcnt(0)" ::: "memory");
    __builtin_amdgcn_sched_barrier(0);

    // ---- PV from LDS (P[*][80..95]=0 makes the V pad rows irrelevant) ----
    floatx4 o[4];
#pragma unroll
    for (int i = 0; i < 4; ++i) o[i] = (floatx4)0.0f;
#pragma unroll
    for (int kt = 0; kt < 3; ++kt) {
        short8 pb = *(const short8*)&p_lds[16 * wave + l16][kt * 32 + quad * 8];
#pragma unroll
        for (int nt = 0; nt < 4; ++nt) {
            short8 vfr = *(const short8*)&V_lds[(nt * 16 + l16) * 128 + (((kt * 4 + quad) ^ rsw) * 8)];
            o[nt] = __builtin_amdgcn_mfma_f32_16x16x32_bf16(pb, vfr, o[nt], 0, 0, 0);
        }
    }

#pragma unroll
    for (int nt = 0; nt < 4; ++nt) {
#pragma unroll
        for (int r = 0; r < 4; ++r) {
            int nr = n0 + 16 * wave + quad * 4 + r;
            attno[((size_t)b * NN + nr) * NINNER + h * NC + nt * 16 + l16] = f2bf(o[nt][r]);
        }
    }
}

extern "C" void kernel_launch(void* const* d_in, const int* in_sizes, int n_in,
                              void* d_out, int out_size, void* d_ws, size_t ws_size,
                              hipStream_t stream) {
    (void)in_sizes; (void)n_in; (void)out_size; (void)ws_size;
    const void* x    = d_in[0];
    const void* key  = d_in[1];
    const void* val  = d_in[2];
    const unsigned char* mask = (const unsigned char*)d_in[3];
    const void* box  = d_in[4];
    const void* road = d_in[5];
    const void* Wq   = d_in[6];
    const void* Wk   = d_in[7];
    const void* Wv   = d_in[8];
    const void* Wo   = d_in[9];
    const void* bo   = d_in[10];

    char* ws = (char*)d_ws;
    size_t off = 0;
    auto carve = [&](size_t bytes) {
        char* p = ws + off;
        off += (bytes + 255) & ~(size_t)255;
        return p;
    };
    int* flag   = (int*)carve(256);
    u16* q_ws   = (u16*)carve((size_t)NB * NN * NINNER * 2);   // 50.3 MB
    u16* k_ws   = (u16*)carve((size_t)NB * NM * NINNER * 2);   // 2.6 MB
    u16* v_ws   = (u16*)carve((size_t)NB * NM * NINNER * 2);   // 2.6 MB
    u16* vT_ws  = (u16*)carve((size_t)NB * NH * NC * 128 * 2); // 4.2 MB (swizzled layout)
    u16* ao_ws  = (u16*)carve((size_t)NB * NN * NINNER * 2);   // 50.3 MB
    u16* x_bf   = ao_ws;  // alias: x_bf dead before attn writes ao_ws
    u16* key_bf = (u16*)carve((size_t)NB * NM * NKD * 2);      // 3.9 MB
    u16* val_bf = (u16*)carve((size_t)NB * NM * NKD * 2);      // 3.9 MB
    u16* Wq_bf  = (u16*)carve((size_t)NINNER * NQD * 2);
    u16* Wk_bf  = (u16*)carve((size_t)NINNER * NKD * 2);
    u16* Wv_bf  = (u16*)carve((size_t)NINNER * NKD * 2);
    u16* WoP_bf = (u16*)carve((size_t)384 * NINNER * 2);
    float* mb   = (float*)carve((size_t)NB * NM * 4);

    prep<<<2, 256, 0, stream>>>((const u16*)x, mask, flag, mb);

    ConvArgs ca;
    ca.s[0] = { x,     x_bf,   (long)NB * NN * NQD, (long)NB * NN * NQD / 2048 };   // 7680
    ca.s[1] = { key,   key_bf, (long)NB * NM * NKD, (long)NB * NM * NKD / 2048 };   // 960
    ca.s[2] = { val,   val_bf, (long)NB * NM * NKD, (long)NB * NM * NKD / 2048 };   // 960
    ca.s[3] = { Wq,    Wq_bf,  (long)NINNER * NQD,  (long)NINNER * NQD / 2048 };    // 80
    ca.s[4] = { Wk,    Wk_bf,  (long)NINNER * NKD,  (long)NINNER * NKD / 2048 };    // 192
    ca.s[5] = { Wv,    Wv_bf,  (long)NINNER * NKD,  (long)NINNER * NKD / 2048 };    // 192
    ca.s[6] = { Wo,    WoP_bf, (long)NQD * NINNER,  (long)384 * NINNER / 2048 };    // 96 (pad rows 320..383)
    long totblk = 0;
    for (int i = 0; i < 7; ++i) totblk += ca.s[i].nblk;
    conv_batch<<<(int)totblk, 256, 0, stream>>>(ca, flag);

    GemmRoles g;
    g.A[0] = key_bf; g.B[0] = Wk_bf; g.C[0] = k_ws; g.mblk[0] = NB * NM / 128; g.kdim[0] = NKD;
    g.A[1] = val_bf; g.B[1] = Wv_bf; g.C[1] = v_ws; g.mblk[1] = NB * NM / 128; g.kdim[1] = NKD;
    g.A[2] = x_bf;   g.B[2] = Wq_bf; g.C[2] = q_ws; g.mblk[2] = NB * NN / 128; g.kdim[2] = NQD;
    g.start[0] = 0;
    g.start[1] = g.mblk[0] * 4;
    g.start[2] = g.start[1] + g.mblk[1] * 4;
    int gtot = g.start[2] + g.mblk[2] * 4;
    gemm_qkv<<<gtot, 256, 0, stream>>>(g);

    transpose_v<<<NB * NH, 256, 0, stream>>>(v_ws, vT_ws);
    attn_kernel<<<dim3(NN / 64, NH, NB), 256, 0, stream>>>(
        q_ws, k_ws, vT_ws, mb, box, road, ao_ws, flag);
    gemm_out<<<dim3(NB * NN / 128, 384 / 128), 256, 0, stream>>>(
        ao_ws, WoP_bf, bo, d_out, flag);
}